// Round 2
// baseline (2281.644 us; speedup 1.0000x reference)
//
#include <hip/hip_runtime.h>
#include <hip/hip_bf16.h>
#include <stdint.h>

// SlotAttention on MI355X. All GEMMs: C[M,N] = X[M,K] @ W[N,K]^T (B^T form),
// bf16 MFMA 16x16x32, fp32 accumulate, m97 structure (128x128 tile, BK=32,
// global_load_lds width=16). Master slots state = fp32 in d_out.
// Workspace budget ~125 MB (R1's 277 MB presumably overflowed ws_size -> fault).
// GRU: r,z via concat GEMM [updates|slots]@[Wih;Whh]^T with fused sigmoid;
// n-gate + state update fused into the i_n GEMM epilogue.
// MLP split into two H=2048 halves to shrink the h1 buffer.

using bf16 = __hip_bfloat16;
typedef __bf16 bf16x8 __attribute__((ext_vector_type(8)));
typedef float f32x4 __attribute__((ext_vector_type(4)));

#define F_RELU    1
#define F_SIGMOID 2
#define F_GRU     4

__device__ __forceinline__ void gl_to_lds16(const void* g, void* l) {
  __builtin_amdgcn_global_load_lds(
      (const __attribute__((address_space(1))) uint32_t*)(uintptr_t)g,
      (__attribute__((address_space(3))) uint32_t*)(uintptr_t)l,
      16, 0, 0);
}

// C[M,N] = scale*(X[M,K] @ W[N,K]^T) + bias[N], with strided inputs/outputs.
// flags: relu | sigmoid | gru-fused-epilogue. resid uses ldf.
__global__ __launch_bounds__(256) void gemm_bt(
    const bf16* __restrict__ X, int ldx,
    const bf16* __restrict__ W, int ldw,
    const float* __restrict__ bias,
    int M, int N, int K, float scale, int flags,
    float* __restrict__ outF, int ldf,
    bf16* __restrict__ outB, int ldb,
    bf16* __restrict__ outT, int ldt,
    const float* __restrict__ resid,
    const bf16* __restrict__ rz,   // F_GRU: sigmoided r|z, ld 2048
    const bf16* __restrict__ hn)   // F_GRU: h_n pre-act, ld 1024
{
  __shared__ __align__(16) bf16 As[128 * 32];
  __shared__ __align__(16) bf16 Bs[128 * 32];
  const int t = threadIdx.x;
  const int m0 = blockIdx.x * 128, n0 = blockIdx.y * 128;
  const int wave = t >> 6, lane = t & 63;
  const int wm = (wave >> 1) * 64, wn = (wave & 1) * 64;
  const int lrow = lane & 15, quad = lane >> 4;

  f32x4 acc[4][4] = {};

  // staging: thread t loads 16B: row = t/4 (+64 for 2nd half), col8 = (t%4)*8
  const int srow = t >> 2;
  const int scol = (t & 3) * 8;
  const bf16* Ag  = X + (size_t)(m0 + srow) * ldx + scol;
  const bf16* Ag2 = Ag + (size_t)64 * ldx;
  const bf16* Bg  = W + (size_t)(n0 + srow) * ldw + scol;
  const bf16* Bg2 = Bg + (size_t)64 * ldw;
  bf16* Al  = As + t * 8;   // lane-contiguous per wave (global_load_lds rule)
  bf16* Al2 = Al + 64 * 32;
  bf16* Bl  = Bs + t * 8;
  bf16* Bl2 = Bl + 64 * 32;

  for (int k0 = 0; k0 < K; k0 += 32) {
    gl_to_lds16(Ag + k0, Al);
    gl_to_lds16(Ag2 + k0, Al2);
    gl_to_lds16(Bg + k0, Bl);
    gl_to_lds16(Bg2 + k0, Bl2);
    __syncthreads();
    bf16x8 af[4], bfr[4];
    const bf16x8* Asv = (const bf16x8*)As;
    const bf16x8* Bsv = (const bf16x8*)Bs;
#pragma unroll
    for (int i = 0; i < 4; i++) af[i]  = Asv[(wm + i * 16 + lrow) * 4 + quad];
#pragma unroll
    for (int j = 0; j < 4; j++) bfr[j] = Bsv[(wn + j * 16 + lrow) * 4 + quad];
#pragma unroll
    for (int i = 0; i < 4; i++)
#pragma unroll
      for (int j = 0; j < 4; j++)
        acc[i][j] = __builtin_amdgcn_mfma_f32_16x16x32_bf16(af[i], bfr[j], acc[i][j], 0, 0, 0);
    __syncthreads();
  }

#pragma unroll
  for (int i = 0; i < 4; i++) {
    const int row0 = m0 + wm + i * 16 + quad * 4;
#pragma unroll
    for (int j = 0; j < 4; j++) {
      const int col = n0 + wn + j * 16 + lrow;
      const float badd = bias ? bias[col] : 0.f;
#pragma unroll
      for (int r = 0; r < 4; r++) {
        const int row = row0 + r;
        float val = acc[i][j][r] * scale + badd;
        if (flags & F_RELU)    val = fmaxf(val, 0.f);
        if (flags & F_SIGMOID) val = 1.f / (1.f + expf(-val));
        if (flags & F_GRU) {
          // val = i_n pre-act; col in [0,1024)
          const size_t ridx = (size_t)row * 1024 + col;
          const float rg = __bfloat162float(rz[(size_t)row * 2048 + col]);
          const float zg = __bfloat162float(rz[(size_t)row * 2048 + 1024 + col]);
          const float hv = __bfloat162float(hn[ridx]);
          const float ng = tanhf(val + rg * hv);
          const float prev = resid[ridx];
          val = (1.f - zg) * ng + zg * prev;
        } else if (resid) {
          val += resid[(size_t)row * ldf + col];
        }
        if (outF) outF[(size_t)row * ldf + col] = val;
        if (outB) outB[(size_t)row * ldb + col] = __float2bfloat16(val);
        if (outT) outT[(size_t)col * ldt + row] = __float2bfloat16(val);
      }
    }
  }
}

// LayerNorm over D=1024, one block (256 thr) per row, bf16 out.
__global__ __launch_bounds__(256) void ln_rows(const float* __restrict__ x,
    const float* __restrict__ g, const float* __restrict__ b,
    bf16* __restrict__ out)
{
  const int row = blockIdx.x;
  const int t = threadIdx.x;
  const float* xr = x + (size_t)row * 1024;
  float v[4];
  float s = 0.f, s2 = 0.f;
#pragma unroll
  for (int i = 0; i < 4; i++) {
    float val = xr[t + 256 * i];
    v[i] = val; s += val; s2 += val * val;
  }
#pragma unroll
  for (int off = 32; off > 0; off >>= 1) {
    s  += __shfl_down(s, off);
    s2 += __shfl_down(s2, off);
  }
  __shared__ float rs[4], rs2[4];
  if ((t & 63) == 0) { rs[t >> 6] = s; rs2[t >> 6] = s2; }
  __syncthreads();
  const float S  = rs[0] + rs[1] + rs[2] + rs[3];
  const float S2 = rs2[0] + rs2[1] + rs2[2] + rs2[3];
  const float mean = S * (1.f / 1024.f);
  const float var  = S2 * (1.f / 1024.f) - mean * mean;
  const float rstd = rsqrtf(var + 1e-5f);
  bf16* outr = out + (size_t)row * 1024;
#pragma unroll
  for (int i = 0; i < 4; i++) {
    const int c = t + 256 * i;
    outr[c] = __float2bfloat16((v[i] - mean) * rstd * g[c] + b[c]);
  }
}

// softmax over slots axis i of dots[b][i][j] (i=128). One thread per (b,j).
__global__ __launch_bounds__(256) void softmax_slots(float* __restrict__ dots)
{
  const int gid = blockIdx.x * 256 + threadIdx.x;   // 64*512 threads
  const int b = gid >> 9, j = gid & 511;
  float* p = dots + (size_t)b * (128 * 512) + j;
  float mx = -1e30f;
  for (int i = 0; i < 128; i++) mx = fmaxf(mx, p[(size_t)i * 512]);
  float s = 0.f;
  for (int i = 0; i < 128; i++) s += expf(p[(size_t)i * 512] - mx);
  const float inv = 1.f / s;
  for (int i = 0; i < 128; i++) p[(size_t)i * 512] = expf(p[(size_t)i * 512] - mx) * inv;
}

// attn = (sm + EPS) / sum_j(sm + EPS); one block per row (b,i), J=512; bf16 out.
__global__ __launch_bounds__(256) void attn_norm(const float* __restrict__ sm,
                                                 bf16* __restrict__ attn)
{
  const int row = blockIdx.x;
  const int t = threadIdx.x;
  const float* p = sm + (size_t)row * 512;
  const float a0 = p[t], a1 = p[t + 256];
  float s = a0 + a1;
#pragma unroll
  for (int off = 32; off > 0; off >>= 1) s += __shfl_down(s, off);
  __shared__ float rs[4];
  if ((t & 63) == 0) rs[t >> 6] = s;
  __syncthreads();
  const float total = rs[0] + rs[1] + rs[2] + rs[3] + 512.f * 1e-8f;
  const float inv = 1.f / total;
  attn[(size_t)row * 512 + t]       = __float2bfloat16((a0 + 1e-8f) * inv);
  attn[(size_t)row * 512 + t + 256] = __float2bfloat16((a1 + 1e-8f) * inv);
}

// slots init: fp32 master + bf16 mirror into Xcat right half (xr ld 2048).
__global__ __launch_bounds__(256) void init_slots(const float* __restrict__ x,
    float* __restrict__ sf, bf16* __restrict__ xr)
{
  const size_t base = (size_t)blockIdx.x * 1024 + threadIdx.x;
#pragma unroll
  for (int i = 0; i < 4; i++) {
    const size_t idx = base + 256 * i;
    const float v = x[idx];
    sf[idx] = v;
    xr[(idx >> 10) * 2048 + (idx & 1023)] = __float2bfloat16(v);
  }
}

__global__ __launch_bounds__(256) void f2b(const float* __restrict__ x,
                                           bf16* __restrict__ y)
{
  const size_t base = (size_t)blockIdx.x * 1024 + threadIdx.x;
#pragma unroll
  for (int i = 0; i < 4; i++) y[base + 256 * i] = __float2bfloat16(x[base + 256 * i]);
}

// wcat[n][0:1024]=Wih[n], wcat[n][1024:2048]=Whh[n]  (n in [0,2048))
__global__ __launch_bounds__(256) void make_wcat(const float* __restrict__ Wih,
    const float* __restrict__ Whh, bf16* __restrict__ wcat)
{
  const int idx = blockIdx.x * 256 + threadIdx.x;  // 2048*1024
  const int n = idx >> 10, c = idx & 1023;
  wcat[(size_t)n * 2048 + c]        = __float2bfloat16(Wih[(size_t)n * 1024 + c]);
  wcat[(size_t)n * 2048 + 1024 + c] = __float2bfloat16(Whh[(size_t)n * 1024 + c]);
}

__global__ __launch_bounds__(256) void make_brz(const float* __restrict__ bih,
    const float* __restrict__ bhh, float* __restrict__ brz)
{
  const int n = blockIdx.x * 256 + threadIdx.x;  // 2048
  brz[n] = bih[n] + bhh[n];
}

extern "C" void kernel_launch(void* const* d_in, const int* in_sizes, int n_in,
                              void* d_out, int out_size, void* d_ws, size_t ws_size,
                              hipStream_t stream)
{
  const float* inputs = (const float*)d_in[0];
  const float* texts  = (const float*)d_in[1];
  const float* Wq  = (const float*)d_in[2];  const float* bq  = (const float*)d_in[3];
  const float* Wk  = (const float*)d_in[4];  const float* bk  = (const float*)d_in[5];
  const float* Wv  = (const float*)d_in[6];  const float* bv  = (const float*)d_in[7];
  const float* Wih = (const float*)d_in[8];  const float* bih = (const float*)d_in[9];
  const float* Whh = (const float*)d_in[10]; const float* bhh = (const float*)d_in[11];
  const float* W1  = (const float*)d_in[12]; const float* b1  = (const float*)d_in[13];
  const float* W2  = (const float*)d_in[14]; const float* b2  = (const float*)d_in[15];
  const float* g_in = (const float*)d_in[16]; const float* be_in = (const float*)d_in[17];
  const float* g_sl = (const float*)d_in[18]; const float* be_sl = (const float*)d_in[19];
  const float* g_ff = (const float*)d_in[20]; const float* be_ff = (const float*)d_in[21];

  constexpr int B = 64, N = 128, J = 512, D = 1024, H = 4096;
  constexpr int M = B * N;   // 8192 rows
  const float SCALE = 0.03125f;  // 1024^-0.5

  char* ws = (char*)d_ws;
  size_t off = 0;
  auto alloc = [&](size_t bytes) -> char* {
    char* p = ws + off; off += (bytes + 255) & ~(size_t)255; return p;
  };
  // persistent (~69 MB)
  bf16* wq_b   = (bf16*)alloc((size_t)D * D * 2);          // 2 MB
  bf16* wk_b   = (bf16*)alloc((size_t)D * D * 2);
  bf16* wv_b   = (bf16*)alloc((size_t)D * D * 2);
  bf16* w1_b   = (bf16*)alloc((size_t)H * D * 2);          // 8 MB
  bf16* w2_b   = (bf16*)alloc((size_t)D * H * 2);          // 8 MB
  bf16* wcat_b = (bf16*)alloc((size_t)2048 * 2048 * 2);    // 8 MB  [Wih;Whh] rows 0..2047
  bf16* whn_b  = (bf16*)alloc((size_t)D * D * 2);          // 2 MB  Whh rows 2048..3071
  bf16* win_b  = (bf16*)alloc((size_t)D * D * 2);          // 2 MB  Wih rows 2048..3071
  float* brz_b = (float*)alloc((size_t)2048 * 4);
  bf16* texts_b = (bf16*)alloc((size_t)J * D * 2);         // 1 MB
  bf16* k_b    = (bf16*)alloc((size_t)J * D * 2);          // 1 MB
  bf16* vT_b   = (bf16*)alloc((size_t)D * J * 2);          // 1 MB
  bf16* xcat_b = (bf16*)alloc((size_t)M * 2048 * 2);       // 32 MB [updates | slots_bf16]
  // phase-overlapped union U (56 MB)
  char* U = alloc((size_t)56 * 1024 * 1024);
  bf16*  xln_b  = (bf16*)(U);                              // 16 MB (attn + mlp phases)
  bf16*  q_b    = (bf16*)(U + (size_t)16 * 1024 * 1024);   // 16 MB
  float* dots_f = (float*)(U + (size_t)32 * 1024 * 1024);  // 16 MB
  bf16*  attn_b = (bf16*)(U + (size_t)48 * 1024 * 1024);   // 8 MB
  bf16*  rz_b   = (bf16*)(U);                              // 32 MB (gru phase)
  bf16*  hn_b   = (bf16*)(U + (size_t)32 * 1024 * 1024);   // 16 MB
  bf16*  h1_b   = (bf16*)(U + (size_t)16 * 1024 * 1024);   // 32 MB (mlp phase)

  if (ws_size < off) return;  // fail loudly (poison absmax) instead of faulting

  float* slots_f = (float*)d_out;   // master fp32 state

  // ---- weight prep ----
  f2b<<<dim3(D * D / 1024), 256, 0, stream>>>(Wq, wq_b);
  f2b<<<dim3(D * D / 1024), 256, 0, stream>>>(Wk, wk_b);
  f2b<<<dim3(D * D / 1024), 256, 0, stream>>>(Wv, wv_b);
  f2b<<<dim3(H * D / 1024), 256, 0, stream>>>(W1, w1_b);
  f2b<<<dim3(D * H / 1024), 256, 0, stream>>>(W2, w2_b);
  f2b<<<dim3(D * D / 1024), 256, 0, stream>>>(Whh + (size_t)2048 * D, whn_b);
  f2b<<<dim3(D * D / 1024), 256, 0, stream>>>(Wih + (size_t)2048 * D, win_b);
  make_wcat<<<dim3(2048 * 1024 / 256), 256, 0, stream>>>(Wih, Whh, wcat_b);
  make_brz<<<dim3(8), 256, 0, stream>>>(bih, bhh, brz_b);

  // ---- slots init (fp32 master + bf16 mirror in Xcat right half) ----
  init_slots<<<dim3(M * D / 1024), 256, 0, stream>>>(inputs, slots_f, xcat_b + 1024);

  // ---- texts LN -> k, v (v stored transposed [D][J]) ----
  ln_rows<<<dim3(J), 256, 0, stream>>>(texts, g_in, be_in, texts_b);
  gemm_bt<<<dim3(J / 128, D / 128), 256, 0, stream>>>(
      texts_b, D, wk_b, D, bk, J, D, D, 1.f, 0,
      nullptr, 0, k_b, D, nullptr, 0, nullptr, nullptr, nullptr);
  gemm_bt<<<dim3(J / 128, D / 128), 256, 0, stream>>>(
      texts_b, D, wv_b, D, bv, J, D, D, 1.f, 0,
      nullptr, 0, nullptr, 0, vT_b, J, nullptr, nullptr, nullptr);

  for (int it = 0; it < 3; it++) {
    // q = LN(slots) @ Wq^T + bq
    ln_rows<<<dim3(M), 256, 0, stream>>>(slots_f, g_sl, be_sl, xln_b);
    gemm_bt<<<dim3(M / 128, D / 128), 256, 0, stream>>>(
        xln_b, D, wq_b, D, bq, M, D, D, 1.f, 0,
        nullptr, 0, q_b, D, nullptr, 0, nullptr, nullptr, nullptr);
    // dots = q @ k^T * SCALE
    gemm_bt<<<dim3(M / 128, J / 128), 256, 0, stream>>>(
        q_b, D, k_b, D, nullptr, M, J, D, SCALE, 0,
        dots_f, J, nullptr, 0, nullptr, 0, nullptr, nullptr, nullptr);
    softmax_slots<<<dim3(B * J / 256), 256, 0, stream>>>(dots_f);
    attn_norm<<<dim3(M), 256, 0, stream>>>(dots_f, attn_b);
    // updates = attn @ v -> Xcat left half (ld 2048)
    gemm_bt<<<dim3(M / 128, D / 128), 256, 0, stream>>>(
        attn_b, J, vT_b, J, nullptr, M, D, J, 1.f, 0,
        nullptr, 0, xcat_b, 2048, nullptr, 0, nullptr, nullptr, nullptr);
    // GRU: rz = sigmoid([updates|slots] @ [Wih;Whh]_rz^T + brz)
    gemm_bt<<<dim3(M / 128, 2048 / 128), 256, 0, stream>>>(
        xcat_b, 2048, wcat_b, 2048, brz_b, M, 2048, 2048, 1.f, F_SIGMOID,
        nullptr, 0, rz_b, 2048, nullptr, 0, nullptr, nullptr, nullptr);
    // h_n = slots @ Whh_n^T + bhh_n
    gemm_bt<<<dim3(M / 128, D / 128), 256, 0, stream>>>(
        xcat_b + 1024, 2048, whn_b, D, bhh + 2048, M, D, D, 1.f, 0,
        nullptr, 0, hn_b, D, nullptr, 0, nullptr, nullptr, nullptr);
    // i_n GEMM + fused GRU epilogue -> slots_f (fp32) + Xcat right half (bf16)
    gemm_bt<<<dim3(M / 128, D / 128), 256, 0, stream>>>(
        xcat_b, 2048, win_b, D, bih + 2048, M, D, D, 1.f, F_GRU,
        slots_f, D, xcat_b + 1024, 2048, nullptr, 0, slots_f, rz_b, hn_b);
    // MLP residual, H split into two 2048 halves
    ln_rows<<<dim3(M), 256, 0, stream>>>(slots_f, g_ff, be_ff, xln_b);
    gemm_bt<<<dim3(M / 128, 2048 / 128), 256, 0, stream>>>(
        xln_b, D, w1_b, D, b1, M, 2048, D, 1.f, F_RELU,
        nullptr, 0, h1_b, 2048, nullptr, 0, nullptr, nullptr, nullptr);
    gemm_bt<<<dim3(M / 128, D / 128), 256, 0, stream>>>(
        h1_b, 2048, w2_b, H, b2, M, D, 2048, 1.f, 0,
        slots_f, D, nullptr, 0, nullptr, 0, slots_f, nullptr, nullptr);
    gemm_bt<<<dim3(M / 128, 2048 / 128), 256, 0, stream>>>(
        xln_b, D, w1_b + (size_t)2048 * D, D, b1 + 2048, M, 2048, D, 1.f, F_RELU,
        nullptr, 0, h1_b, 2048, nullptr, 0, nullptr, nullptr, nullptr);
    gemm_bt<<<dim3(M / 128, D / 128), 256, 0, stream>>>(
        h1_b, 2048, w2_b + 2048, H, nullptr, M, D, 2048, 1.f, 0,
        slots_f, D, xcat_b + 1024, 2048, nullptr, 0, slots_f, nullptr, nullptr);
  }
}

// Round 3
// 2113.915 us; speedup vs baseline: 1.0793x; 1.0793x over previous
//
#include <hip/hip_runtime.h>
#include <hip/hip_bf16.h>
#include <stdint.h>

// SlotAttention on MI355X. All GEMMs: C[M,N] = X[M,K] @ W[N,K]^T (B^T form),
// bf16 MFMA 16x16x32, fp32 accumulate, m97 structure (BK=32,
// global_load_lds width=16). Master slots state = fp32 in d_out.
// R3: templated tile width BN. 128x128 for N>=2048 GEMMs (grid already 4/CU),
// 128x64 for N=1024/512 GEMMs -> doubles blocks/CU from 2 to 4 (R2 counters:
// occupancy 23%, MfmaUtil 20% on W2-type dispatches = latency-bound at 2/CU).
// Workspace ~125 MB (known-safe; 277 MB faulted in R1).

using bf16 = __hip_bfloat16;
typedef __bf16 bf16x8 __attribute__((ext_vector_type(8)));
typedef float f32x4 __attribute__((ext_vector_type(4)));

#define F_RELU    1
#define F_SIGMOID 2
#define F_GRU     4

__device__ __forceinline__ void gl_to_lds16(const void* g, void* l) {
  __builtin_amdgcn_global_load_lds(
      (const __attribute__((address_space(1))) uint32_t*)(uintptr_t)g,
      (__attribute__((address_space(3))) uint32_t*)(uintptr_t)l,
      16, 0, 0);
}

// C[M,N] = scale*(X[M,K] @ W[N,K]^T) + bias[N], strided in/out.
// Tile: 128 x BN, 4 waves as 2x2, each wave 64 x BN/2 (4 x BN/32 MFMA frags).
template <int BN>
__global__ __launch_bounds__(256) void gemm_bt(
    const bf16* __restrict__ X, int ldx,
    const bf16* __restrict__ W, int ldw,
    const float* __restrict__ bias,
    int M, int N, int K, float scale, int flags,
    float* __restrict__ outF, int ldf,
    bf16* __restrict__ outB, int ldb,
    bf16* __restrict__ outT, int ldt,
    const float* __restrict__ resid,
    const bf16* __restrict__ rz,   // F_GRU: sigmoided r|z, ld 2048
    const bf16* __restrict__ hn)   // F_GRU: h_n pre-act, ld 1024
{
  constexpr int NJ = BN / 32;     // MFMA n-frags per wave
  __shared__ __align__(16) bf16 As[128 * 32];
  __shared__ __align__(16) bf16 Bs[BN * 32];
  const int t = threadIdx.x;
  const int m0 = blockIdx.x * 128, n0 = blockIdx.y * BN;
  const int wave = t >> 6, lane = t & 63;
  const int wm = (wave >> 1) * 64, wn = (wave & 1) * (BN / 2);
  const int lrow = lane & 15, quad = lane >> 4;

  f32x4 acc[4][NJ] = {};

  // staging: thread t loads 16B: row = t/4, col8 = (t%4)*8
  const int srow = t >> 2;
  const int scol = (t & 3) * 8;
  const bf16* Ag  = X + (size_t)(m0 + srow) * ldx + scol;
  const bf16* Ag2 = Ag + (size_t)64 * ldx;
  const bf16* Bg  = W + (size_t)(n0 + srow) * ldw + scol;
  const bf16* Bg2 = Bg + (size_t)64 * ldw;   // only BN==128
  bf16* Al  = As + t * 8;   // lane-contiguous per wave (global_load_lds rule)
  bf16* Al2 = Al + 64 * 32;
  bf16* Bl  = Bs + t * 8;
  bf16* Bl2 = Bl + 64 * 32;

  for (int k0 = 0; k0 < K; k0 += 32) {
    gl_to_lds16(Ag + k0, Al);
    gl_to_lds16(Ag2 + k0, Al2);
    gl_to_lds16(Bg + k0, Bl);
    if (BN == 128) gl_to_lds16(Bg2 + k0, Bl2);
    __syncthreads();
    bf16x8 af[4], bfr[NJ];
    const bf16x8* Asv = (const bf16x8*)As;
    const bf16x8* Bsv = (const bf16x8*)Bs;
#pragma unroll
    for (int i = 0; i < 4; i++)  af[i]  = Asv[(wm + i * 16 + lrow) * 4 + quad];
#pragma unroll
    for (int j = 0; j < NJ; j++) bfr[j] = Bsv[(wn + j * 16 + lrow) * 4 + quad];
#pragma unroll
    for (int i = 0; i < 4; i++)
#pragma unroll
      for (int j = 0; j < NJ; j++)
        acc[i][j] = __builtin_amdgcn_mfma_f32_16x16x32_bf16(af[i], bfr[j], acc[i][j], 0, 0, 0);
    __syncthreads();
  }

#pragma unroll
  for (int i = 0; i < 4; i++) {
    const int row0 = m0 + wm + i * 16 + quad * 4;
#pragma unroll
    for (int j = 0; j < NJ; j++) {
      const int col = n0 + wn + j * 16 + lrow;
      const float badd = bias ? bias[col] : 0.f;
#pragma unroll
      for (int r = 0; r < 4; r++) {
        const int row = row0 + r;
        float val = acc[i][j][r] * scale + badd;
        if (flags & F_RELU)    val = fmaxf(val, 0.f);
        if (flags & F_SIGMOID) val = 1.f / (1.f + expf(-val));
        if (flags & F_GRU) {
          // val = i_n pre-act; col in [0,1024)
          const size_t ridx = (size_t)row * 1024 + col;
          const float rg = __bfloat162float(rz[(size_t)row * 2048 + col]);
          const float zg = __bfloat162float(rz[(size_t)row * 2048 + 1024 + col]);
          const float hv = __bfloat162float(hn[ridx]);
          const float ng = tanhf(val + rg * hv);
          const float prev = resid[ridx];
          val = (1.f - zg) * ng + zg * prev;
        } else if (resid) {
          val += resid[(size_t)row * ldf + col];
        }
        if (outF) outF[(size_t)row * ldf + col] = val;
        if (outB) outB[(size_t)row * ldb + col] = __float2bfloat16(val);
        if (outT) outT[(size_t)col * ldt + row] = __float2bfloat16(val);
      }
    }
  }
}

// LayerNorm over D=1024, one block (256 thr) per row, bf16 out.
__global__ __launch_bounds__(256) void ln_rows(const float* __restrict__ x,
    const float* __restrict__ g, const float* __restrict__ b,
    bf16* __restrict__ out)
{
  const int row = blockIdx.x;
  const int t = threadIdx.x;
  const float* xr = x + (size_t)row * 1024;
  float v[4];
  float s = 0.f, s2 = 0.f;
#pragma unroll
  for (int i = 0; i < 4; i++) {
    float val = xr[t + 256 * i];
    v[i] = val; s += val; s2 += val * val;
  }
#pragma unroll
  for (int off = 32; off > 0; off >>= 1) {
    s  += __shfl_down(s, off);
    s2 += __shfl_down(s2, off);
  }
  __shared__ float rs[4], rs2[4];
  if ((t & 63) == 0) { rs[t >> 6] = s; rs2[t >> 6] = s2; }
  __syncthreads();
  const float S  = rs[0] + rs[1] + rs[2] + rs[3];
  const float S2 = rs2[0] + rs2[1] + rs2[2] + rs2[3];
  const float mean = S * (1.f / 1024.f);
  const float var  = S2 * (1.f / 1024.f) - mean * mean;
  const float rstd = rsqrtf(var + 1e-5f);
  bf16* outr = out + (size_t)row * 1024;
#pragma unroll
  for (int i = 0; i < 4; i++) {
    const int c = t + 256 * i;
    outr[c] = __float2bfloat16((v[i] - mean) * rstd * g[c] + b[c]);
  }
}

// softmax over slots axis i of dots[b][i][j] (i=128). One thread per (b,j).
__global__ __launch_bounds__(256) void softmax_slots(float* __restrict__ dots)
{
  const int gid = blockIdx.x * 256 + threadIdx.x;   // 64*512 threads
  const int b = gid >> 9, j = gid & 511;
  float* p = dots + (size_t)b * (128 * 512) + j;
  float mx = -1e30f;
  for (int i = 0; i < 128; i++) mx = fmaxf(mx, p[(size_t)i * 512]);
  float s = 0.f;
  for (int i = 0; i < 128; i++) s += expf(p[(size_t)i * 512] - mx);
  const float inv = 1.f / s;
  for (int i = 0; i < 128; i++) p[(size_t)i * 512] = expf(p[(size_t)i * 512] - mx) * inv;
}

// attn = (sm + EPS) / sum_j(sm + EPS); one block per row (b,i), J=512; bf16 out.
__global__ __launch_bounds__(256) void attn_norm(const float* __restrict__ sm,
                                                 bf16* __restrict__ attn)
{
  const int row = blockIdx.x;
  const int t = threadIdx.x;
  const float* p = sm + (size_t)row * 512;
  const float a0 = p[t], a1 = p[t + 256];
  float s = a0 + a1;
#pragma unroll
  for (int off = 32; off > 0; off >>= 1) s += __shfl_down(s, off);
  __shared__ float rs[4];
  if ((t & 63) == 0) rs[t >> 6] = s;
  __syncthreads();
  const float total = rs[0] + rs[1] + rs[2] + rs[3] + 512.f * 1e-8f;
  const float inv = 1.f / total;
  attn[(size_t)row * 512 + t]       = __float2bfloat16((a0 + 1e-8f) * inv);
  attn[(size_t)row * 512 + t + 256] = __float2bfloat16((a1 + 1e-8f) * inv);
}

// slots init: fp32 master + bf16 mirror into Xcat right half (xr ld 2048).
__global__ __launch_bounds__(256) void init_slots(const float* __restrict__ x,
    float* __restrict__ sf, bf16* __restrict__ xr)
{
  const size_t base = (size_t)blockIdx.x * 1024 + threadIdx.x;
#pragma unroll
  for (int i = 0; i < 4; i++) {
    const size_t idx = base + 256 * i;
    const float v = x[idx];
    sf[idx] = v;
    xr[(idx >> 10) * 2048 + (idx & 1023)] = __float2bfloat16(v);
  }
}

__global__ __launch_bounds__(256) void f2b(const float* __restrict__ x,
                                           bf16* __restrict__ y)
{
  const size_t base = (size_t)blockIdx.x * 1024 + threadIdx.x;
#pragma unroll
  for (int i = 0; i < 4; i++) y[base + 256 * i] = __float2bfloat16(x[base + 256 * i]);
}

// wcat[n][0:1024]=Wih[n], wcat[n][1024:2048]=Whh[n]  (n in [0,2048))
__global__ __launch_bounds__(256) void make_wcat(const float* __restrict__ Wih,
    const float* __restrict__ Whh, bf16* __restrict__ wcat)
{
  const int idx = blockIdx.x * 256 + threadIdx.x;  // 2048*1024
  const int n = idx >> 10, c = idx & 1023;
  wcat[(size_t)n * 2048 + c]        = __float2bfloat16(Wih[(size_t)n * 1024 + c]);
  wcat[(size_t)n * 2048 + 1024 + c] = __float2bfloat16(Whh[(size_t)n * 1024 + c]);
}

__global__ __launch_bounds__(256) void make_brz(const float* __restrict__ bih,
    const float* __restrict__ bhh, float* __restrict__ brz)
{
  const int n = blockIdx.x * 256 + threadIdx.x;  // 2048
  brz[n] = bih[n] + bhh[n];
}

extern "C" void kernel_launch(void* const* d_in, const int* in_sizes, int n_in,
                              void* d_out, int out_size, void* d_ws, size_t ws_size,
                              hipStream_t stream)
{
  const float* inputs = (const float*)d_in[0];
  const float* texts  = (const float*)d_in[1];
  const float* Wq  = (const float*)d_in[2];  const float* bq  = (const float*)d_in[3];
  const float* Wk  = (const float*)d_in[4];  const float* bk  = (const float*)d_in[5];
  const float* Wv  = (const float*)d_in[6];  const float* bv  = (const float*)d_in[7];
  const float* Wih = (const float*)d_in[8];  const float* bih = (const float*)d_in[9];
  const float* Whh = (const float*)d_in[10]; const float* bhh = (const float*)d_in[11];
  const float* W1  = (const float*)d_in[12]; const float* b1  = (const float*)d_in[13];
  const float* W2  = (const float*)d_in[14]; const float* b2  = (const float*)d_in[15];
  const float* g_in = (const float*)d_in[16]; const float* be_in = (const float*)d_in[17];
  const float* g_sl = (const float*)d_in[18]; const float* be_sl = (const float*)d_in[19];
  const float* g_ff = (const float*)d_in[20]; const float* be_ff = (const float*)d_in[21];

  constexpr int B = 64, N = 128, J = 512, D = 1024, H = 4096;
  constexpr int M = B * N;   // 8192 rows
  const float SCALE = 0.03125f;  // 1024^-0.5

  char* ws = (char*)d_ws;
  size_t off = 0;
  auto alloc = [&](size_t bytes) -> char* {
    char* p = ws + off; off += (bytes + 255) & ~(size_t)255; return p;
  };
  // persistent (~69 MB)
  bf16* wq_b   = (bf16*)alloc((size_t)D * D * 2);          // 2 MB
  bf16* wk_b   = (bf16*)alloc((size_t)D * D * 2);
  bf16* wv_b   = (bf16*)alloc((size_t)D * D * 2);
  bf16* w1_b   = (bf16*)alloc((size_t)H * D * 2);          // 8 MB
  bf16* w2_b   = (bf16*)alloc((size_t)D * H * 2);          // 8 MB
  bf16* wcat_b = (bf16*)alloc((size_t)2048 * 2048 * 2);    // 8 MB  [Wih;Whh] rows 0..2047
  bf16* whn_b  = (bf16*)alloc((size_t)D * D * 2);          // 2 MB  Whh rows 2048..3071
  bf16* win_b  = (bf16*)alloc((size_t)D * D * 2);          // 2 MB  Wih rows 2048..3071
  float* brz_b = (float*)alloc((size_t)2048 * 4);
  bf16* texts_b = (bf16*)alloc((size_t)J * D * 2);         // 1 MB
  bf16* k_b    = (bf16*)alloc((size_t)J * D * 2);          // 1 MB
  bf16* vT_b   = (bf16*)alloc((size_t)D * J * 2);          // 1 MB
  bf16* xcat_b = (bf16*)alloc((size_t)M * 2048 * 2);       // 32 MB [updates | slots_bf16]
  // phase-overlapped union U (56 MB)
  char* U = alloc((size_t)56 * 1024 * 1024);
  bf16*  xln_b  = (bf16*)(U);                              // 16 MB (attn + mlp phases)
  bf16*  q_b    = (bf16*)(U + (size_t)16 * 1024 * 1024);   // 16 MB
  float* dots_f = (float*)(U + (size_t)32 * 1024 * 1024);  // 16 MB
  bf16*  attn_b = (bf16*)(U + (size_t)48 * 1024 * 1024);   // 8 MB
  bf16*  rz_b   = (bf16*)(U);                              // 32 MB (gru phase)
  bf16*  hn_b   = (bf16*)(U + (size_t)32 * 1024 * 1024);   // 16 MB
  bf16*  h1_b   = (bf16*)(U + (size_t)16 * 1024 * 1024);   // 32 MB (mlp phase)

  if (ws_size < off) return;  // fail loudly (poison absmax) instead of faulting

  float* slots_f = (float*)d_out;   // master fp32 state

  // ---- weight prep ----
  f2b<<<dim3(D * D / 1024), 256, 0, stream>>>(Wq, wq_b);
  f2b<<<dim3(D * D / 1024), 256, 0, stream>>>(Wk, wk_b);
  f2b<<<dim3(D * D / 1024), 256, 0, stream>>>(Wv, wv_b);
  f2b<<<dim3(H * D / 1024), 256, 0, stream>>>(W1, w1_b);
  f2b<<<dim3(D * H / 1024), 256, 0, stream>>>(W2, w2_b);
  f2b<<<dim3(D * D / 1024), 256, 0, stream>>>(Whh + (size_t)2048 * D, whn_b);
  f2b<<<dim3(D * D / 1024), 256, 0, stream>>>(Wih + (size_t)2048 * D, win_b);
  make_wcat<<<dim3(2048 * 1024 / 256), 256, 0, stream>>>(Wih, Whh, wcat_b);
  make_brz<<<dim3(8), 256, 0, stream>>>(bih, bhh, brz_b);

  // ---- slots init (fp32 master + bf16 mirror in Xcat right half) ----
  init_slots<<<dim3(M * D / 1024), 256, 0, stream>>>(inputs, slots_f, xcat_b + 1024);

  // ---- texts LN -> k, v (v stored transposed [D][J]) ----
  ln_rows<<<dim3(J), 256, 0, stream>>>(texts, g_in, be_in, texts_b);
  gemm_bt<64><<<dim3(J / 128, D / 64), 256, 0, stream>>>(
      texts_b, D, wk_b, D, bk, J, D, D, 1.f, 0,
      nullptr, 0, k_b, D, nullptr, 0, nullptr, nullptr, nullptr);
  gemm_bt<64><<<dim3(J / 128, D / 64), 256, 0, stream>>>(
      texts_b, D, wv_b, D, bv, J, D, D, 1.f, 0,
      nullptr, 0, nullptr, 0, vT_b, J, nullptr, nullptr, nullptr);

  for (int it = 0; it < 3; it++) {
    // q = LN(slots) @ Wq^T + bq
    ln_rows<<<dim3(M), 256, 0, stream>>>(slots_f, g_sl, be_sl, xln_b);
    gemm_bt<64><<<dim3(M / 128, D / 64), 256, 0, stream>>>(
        xln_b, D, wq_b, D, bq, M, D, D, 1.f, 0,
        nullptr, 0, q_b, D, nullptr, 0, nullptr, nullptr, nullptr);
    // dots = q @ k^T * SCALE
    gemm_bt<64><<<dim3(M / 128, J / 64), 256, 0, stream>>>(
        q_b, D, k_b, D, nullptr, M, J, D, SCALE, 0,
        dots_f, J, nullptr, 0, nullptr, 0, nullptr, nullptr, nullptr);
    softmax_slots<<<dim3(B * J / 256), 256, 0, stream>>>(dots_f);
    attn_norm<<<dim3(M), 256, 0, stream>>>(dots_f, attn_b);
    // updates = attn @ v -> Xcat left half (ld 2048)
    gemm_bt<64><<<dim3(M / 128, D / 64), 256, 0, stream>>>(
        attn_b, J, vT_b, J, nullptr, M, D, J, 1.f, 0,
        nullptr, 0, xcat_b, 2048, nullptr, 0, nullptr, nullptr, nullptr);
    // GRU: rz = sigmoid([updates|slots] @ [Wih;Whh]_rz^T + brz)
    gemm_bt<128><<<dim3(M / 128, 2048 / 128), 256, 0, stream>>>(
        xcat_b, 2048, wcat_b, 2048, brz_b, M, 2048, 2048, 1.f, F_SIGMOID,
        nullptr, 0, rz_b, 2048, nullptr, 0, nullptr, nullptr, nullptr);
    // h_n = slots @ Whh_n^T + bhh_n
    gemm_bt<64><<<dim3(M / 128, D / 64), 256, 0, stream>>>(
        xcat_b + 1024, 2048, whn_b, D, bhh + 2048, M, D, D, 1.f, 0,
        nullptr, 0, hn_b, D, nullptr, 0, nullptr, nullptr, nullptr);
    // i_n GEMM + fused GRU epilogue -> slots_f (fp32) + Xcat right half (bf16)
    gemm_bt<64><<<dim3(M / 128, D / 64), 256, 0, stream>>>(
        xcat_b, 2048, win_b, D, bih + 2048, M, D, D, 1.f, F_GRU,
        slots_f, D, xcat_b + 1024, 2048, nullptr, 0, slots_f, rz_b, hn_b);
    // MLP residual, H split into two 2048 halves
    ln_rows<<<dim3(M), 256, 0, stream>>>(slots_f, g_ff, be_ff, xln_b);
    gemm_bt<128><<<dim3(M / 128, 2048 / 128), 256, 0, stream>>>(
        xln_b, D, w1_b, D, b1, M, 2048, D, 1.f, F_RELU,
        nullptr, 0, h1_b, 2048, nullptr, 0, nullptr, nullptr, nullptr);
    gemm_bt<64><<<dim3(M / 128, D / 64), 256, 0, stream>>>(
        h1_b, 2048, w2_b, H, b2, M, D, 2048, 1.f, 0,
        slots_f, D, nullptr, 0, nullptr, 0, slots_f, nullptr, nullptr);
    gemm_bt<128><<<dim3(M / 128, 2048 / 128), 256, 0, stream>>>(
        xln_b, D, w1_b + (size_t)2048 * D, D, b1 + 2048, M, 2048, D, 1.f, F_RELU,
        nullptr, 0, h1_b, 2048, nullptr, 0, nullptr, nullptr, nullptr);
    gemm_bt<64><<<dim3(M / 128, D / 64), 256, 0, stream>>>(
        h1_b, 2048, w2_b + 2048, H, nullptr, M, D, 2048, 1.f, 0,
        slots_f, D, xcat_b + 1024, 2048, nullptr, 0, slots_f, nullptr, nullptr);
  }
}

// Round 4
// 1827.463 us; speedup vs baseline: 1.2485x; 1.1567x over previous
//
#include <hip/hip_runtime.h>
#include <hip/hip_bf16.h>
#include <stdint.h>

// SlotAttention on MI355X. All GEMMs: C[M,N] = X[M,K] @ W[N,K]^T (B^T form),
// bf16 MFMA 16x16x32, fp32 accumulate, m97 structure (BK=32,
// global_load_lds width=16). Master slots state = fp32 in d_out.
// R4: __launch_bounds__(256, 4) on gemm_bt. R3 counters: VGPR 80 + AGPR 64 =
// 144 regs/wave -> 3 blocks/CU -> 768 slots vs 1024-block grids = 1.33 rounds
// (33% tail waste). Capping regs at 128/wave gives 4 blocks/CU = 1024 slots =
// exactly one round for the big GEMMs.
// Workspace ~125 MB (known-safe; 277 MB faulted in R1).

using bf16 = __hip_bfloat16;
typedef __bf16 bf16x8 __attribute__((ext_vector_type(8)));
typedef float f32x4 __attribute__((ext_vector_type(4)));

#define F_RELU    1
#define F_SIGMOID 2
#define F_GRU     4

__device__ __forceinline__ void gl_to_lds16(const void* g, void* l) {
  __builtin_amdgcn_global_load_lds(
      (const __attribute__((address_space(1))) uint32_t*)(uintptr_t)g,
      (__attribute__((address_space(3))) uint32_t*)(uintptr_t)l,
      16, 0, 0);
}

// C[M,N] = scale*(X[M,K] @ W[N,K]^T) + bias[N], strided in/out.
// Tile: 128 x BN, 4 waves as 2x2, each wave 64 x BN/2 (4 x BN/32 MFMA frags).
template <int BN>
__global__ __launch_bounds__(256, 4) void gemm_bt(
    const bf16* __restrict__ X, int ldx,
    const bf16* __restrict__ W, int ldw,
    const float* __restrict__ bias,
    int M, int N, int K, float scale, int flags,
    float* __restrict__ outF, int ldf,
    bf16* __restrict__ outB, int ldb,
    bf16* __restrict__ outT, int ldt,
    const float* __restrict__ resid,
    const bf16* __restrict__ rz,   // F_GRU: sigmoided r|z, ld 2048
    const bf16* __restrict__ hn)   // F_GRU: h_n pre-act, ld 1024
{
  constexpr int NJ = BN / 32;     // MFMA n-frags per wave
  __shared__ __align__(16) bf16 As[128 * 32];
  __shared__ __align__(16) bf16 Bs[BN * 32];
  const int t = threadIdx.x;
  const int m0 = blockIdx.x * 128, n0 = blockIdx.y * BN;
  const int wave = t >> 6, lane = t & 63;
  const int wm = (wave >> 1) * 64, wn = (wave & 1) * (BN / 2);
  const int lrow = lane & 15, quad = lane >> 4;

  f32x4 acc[4][NJ] = {};

  // staging: thread t loads 16B: row = t/4, col8 = (t%4)*8
  const int srow = t >> 2;
  const int scol = (t & 3) * 8;
  const bf16* Ag  = X + (size_t)(m0 + srow) * ldx + scol;
  const bf16* Ag2 = Ag + (size_t)64 * ldx;
  const bf16* Bg  = W + (size_t)(n0 + srow) * ldw + scol;
  const bf16* Bg2 = Bg + (size_t)64 * ldw;   // only BN==128
  bf16* Al  = As + t * 8;   // lane-contiguous per wave (global_load_lds rule)
  bf16* Al2 = Al + 64 * 32;
  bf16* Bl  = Bs + t * 8;
  bf16* Bl2 = Bl + 64 * 32;

  for (int k0 = 0; k0 < K; k0 += 32) {
    gl_to_lds16(Ag + k0, Al);
    gl_to_lds16(Ag2 + k0, Al2);
    gl_to_lds16(Bg + k0, Bl);
    if (BN == 128) gl_to_lds16(Bg2 + k0, Bl2);
    __syncthreads();
    bf16x8 af[4], bfr[NJ];
    const bf16x8* Asv = (const bf16x8*)As;
    const bf16x8* Bsv = (const bf16x8*)Bs;
#pragma unroll
    for (int i = 0; i < 4; i++)  af[i]  = Asv[(wm + i * 16 + lrow) * 4 + quad];
#pragma unroll
    for (int j = 0; j < NJ; j++) bfr[j] = Bsv[(wn + j * 16 + lrow) * 4 + quad];
#pragma unroll
    for (int i = 0; i < 4; i++)
#pragma unroll
      for (int j = 0; j < NJ; j++)
        acc[i][j] = __builtin_amdgcn_mfma_f32_16x16x32_bf16(af[i], bfr[j], acc[i][j], 0, 0, 0);
    __syncthreads();
  }

#pragma unroll
  for (int i = 0; i < 4; i++) {
    const int row0 = m0 + wm + i * 16 + quad * 4;
#pragma unroll
    for (int j = 0; j < NJ; j++) {
      const int col = n0 + wn + j * 16 + lrow;
      const float badd = bias ? bias[col] : 0.f;
#pragma unroll
      for (int r = 0; r < 4; r++) {
        const int row = row0 + r;
        float val = acc[i][j][r] * scale + badd;
        if (flags & F_RELU)    val = fmaxf(val, 0.f);
        if (flags & F_SIGMOID) val = 1.f / (1.f + expf(-val));
        if (flags & F_GRU) {
          // val = i_n pre-act; col in [0,1024)
          const size_t ridx = (size_t)row * 1024 + col;
          const float rg = __bfloat162float(rz[(size_t)row * 2048 + col]);
          const float zg = __bfloat162float(rz[(size_t)row * 2048 + 1024 + col]);
          const float hv = __bfloat162float(hn[ridx]);
          const float ng = tanhf(val + rg * hv);
          const float prev = resid[ridx];
          val = (1.f - zg) * ng + zg * prev;
        } else if (resid) {
          val += resid[(size_t)row * ldf + col];
        }
        if (outF) outF[(size_t)row * ldf + col] = val;
        if (outB) outB[(size_t)row * ldb + col] = __float2bfloat16(val);
        if (outT) outT[(size_t)col * ldt + row] = __float2bfloat16(val);
      }
    }
  }
}

// LayerNorm over D=1024, one block (256 thr) per row, bf16 out.
__global__ __launch_bounds__(256) void ln_rows(const float* __restrict__ x,
    const float* __restrict__ g, const float* __restrict__ b,
    bf16* __restrict__ out)
{
  const int row = blockIdx.x;
  const int t = threadIdx.x;
  const float* xr = x + (size_t)row * 1024;
  float v[4];
  float s = 0.f, s2 = 0.f;
#pragma unroll
  for (int i = 0; i < 4; i++) {
    float val = xr[t + 256 * i];
    v[i] = val; s += val; s2 += val * val;
  }
#pragma unroll
  for (int off = 32; off > 0; off >>= 1) {
    s  += __shfl_down(s, off);
    s2 += __shfl_down(s2, off);
  }
  __shared__ float rs[4], rs2[4];
  if ((t & 63) == 0) { rs[t >> 6] = s; rs2[t >> 6] = s2; }
  __syncthreads();
  const float S  = rs[0] + rs[1] + rs[2] + rs[3];
  const float S2 = rs2[0] + rs2[1] + rs2[2] + rs2[3];
  const float mean = S * (1.f / 1024.f);
  const float var  = S2 * (1.f / 1024.f) - mean * mean;
  const float rstd = rsqrtf(var + 1e-5f);
  bf16* outr = out + (size_t)row * 1024;
#pragma unroll
  for (int i = 0; i < 4; i++) {
    const int c = t + 256 * i;
    outr[c] = __float2bfloat16((v[i] - mean) * rstd * g[c] + b[c]);
  }
}

// softmax over slots axis i of dots[b][i][j] (i=128). One thread per (b,j).
__global__ __launch_bounds__(256) void softmax_slots(float* __restrict__ dots)
{
  const int gid = blockIdx.x * 256 + threadIdx.x;   // 64*512 threads
  const int b = gid >> 9, j = gid & 511;
  float* p = dots + (size_t)b * (128 * 512) + j;
  float mx = -1e30f;
  for (int i = 0; i < 128; i++) mx = fmaxf(mx, p[(size_t)i * 512]);
  float s = 0.f;
  for (int i = 0; i < 128; i++) s += expf(p[(size_t)i * 512] - mx);
  const float inv = 1.f / s;
  for (int i = 0; i < 128; i++) p[(size_t)i * 512] = expf(p[(size_t)i * 512] - mx) * inv;
}

// attn = (sm + EPS) / sum_j(sm + EPS); one block per row (b,i), J=512; bf16 out.
__global__ __launch_bounds__(256) void attn_norm(const float* __restrict__ sm,
                                                 bf16* __restrict__ attn)
{
  const int row = blockIdx.x;
  const int t = threadIdx.x;
  const float* p = sm + (size_t)row * 512;
  const float a0 = p[t], a1 = p[t + 256];
  float s = a0 + a1;
#pragma unroll
  for (int off = 32; off > 0; off >>= 1) s += __shfl_down(s, off);
  __shared__ float rs[4];
  if ((t & 63) == 0) rs[t >> 6] = s;
  __syncthreads();
  const float total = rs[0] + rs[1] + rs[2] + rs[3] + 512.f * 1e-8f;
  const float inv = 1.f / total;
  attn[(size_t)row * 512 + t]       = __float2bfloat16((a0 + 1e-8f) * inv);
  attn[(size_t)row * 512 + t + 256] = __float2bfloat16((a1 + 1e-8f) * inv);
}

// slots init: fp32 master + bf16 mirror into Xcat right half (xr ld 2048).
__global__ __launch_bounds__(256) void init_slots(const float* __restrict__ x,
    float* __restrict__ sf, bf16* __restrict__ xr)
{
  const size_t base = (size_t)blockIdx.x * 1024 + threadIdx.x;
#pragma unroll
  for (int i = 0; i < 4; i++) {
    const size_t idx = base + 256 * i;
    const float v = x[idx];
    sf[idx] = v;
    xr[(idx >> 10) * 2048 + (idx & 1023)] = __float2bfloat16(v);
  }
}

__global__ __launch_bounds__(256) void f2b(const float* __restrict__ x,
                                           bf16* __restrict__ y)
{
  const size_t base = (size_t)blockIdx.x * 1024 + threadIdx.x;
#pragma unroll
  for (int i = 0; i < 4; i++) y[base + 256 * i] = __float2bfloat16(x[base + 256 * i]);
}

// wcat[n][0:1024]=Wih[n], wcat[n][1024:2048]=Whh[n]  (n in [0,2048))
__global__ __launch_bounds__(256) void make_wcat(const float* __restrict__ Wih,
    const float* __restrict__ Whh, bf16* __restrict__ wcat)
{
  const int idx = blockIdx.x * 256 + threadIdx.x;  // 2048*1024
  const int n = idx >> 10, c = idx & 1023;
  wcat[(size_t)n * 2048 + c]        = __float2bfloat16(Wih[(size_t)n * 1024 + c]);
  wcat[(size_t)n * 2048 + 1024 + c] = __float2bfloat16(Whh[(size_t)n * 1024 + c]);
}

__global__ __launch_bounds__(256) void make_brz(const float* __restrict__ bih,
    const float* __restrict__ bhh, float* __restrict__ brz)
{
  const int n = blockIdx.x * 256 + threadIdx.x;  // 2048
  brz[n] = bih[n] + bhh[n];
}

extern "C" void kernel_launch(void* const* d_in, const int* in_sizes, int n_in,
                              void* d_out, int out_size, void* d_ws, size_t ws_size,
                              hipStream_t stream)
{
  const float* inputs = (const float*)d_in[0];
  const float* texts  = (const float*)d_in[1];
  const float* Wq  = (const float*)d_in[2];  const float* bq  = (const float*)d_in[3];
  const float* Wk  = (const float*)d_in[4];  const float* bk  = (const float*)d_in[5];
  const float* Wv  = (const float*)d_in[6];  const float* bv  = (const float*)d_in[7];
  const float* Wih = (const float*)d_in[8];  const float* bih = (const float*)d_in[9];
  const float* Whh = (const float*)d_in[10]; const float* bhh = (const float*)d_in[11];
  const float* W1  = (const float*)d_in[12]; const float* b1  = (const float*)d_in[13];
  const float* W2  = (const float*)d_in[14]; const float* b2  = (const float*)d_in[15];
  const float* g_in = (const float*)d_in[16]; const float* be_in = (const float*)d_in[17];
  const float* g_sl = (const float*)d_in[18]; const float* be_sl = (const float*)d_in[19];
  const float* g_ff = (const float*)d_in[20]; const float* be_ff = (const float*)d_in[21];

  constexpr int B = 64, N = 128, J = 512, D = 1024, H = 4096;
  constexpr int M = B * N;   // 8192 rows
  const float SCALE = 0.03125f;  // 1024^-0.5

  char* ws = (char*)d_ws;
  size_t off = 0;
  auto alloc = [&](size_t bytes) -> char* {
    char* p = ws + off; off += (bytes + 255) & ~(size_t)255; return p;
  };
  // persistent (~69 MB)
  bf16* wq_b   = (bf16*)alloc((size_t)D * D * 2);          // 2 MB
  bf16* wk_b   = (bf16*)alloc((size_t)D * D * 2);
  bf16* wv_b   = (bf16*)alloc((size_t)D * D * 2);
  bf16* w1_b   = (bf16*)alloc((size_t)H * D * 2);          // 8 MB
  bf16* w2_b   = (bf16*)alloc((size_t)D * H * 2);          // 8 MB
  bf16* wcat_b = (bf16*)alloc((size_t)2048 * 2048 * 2);    // 8 MB  [Wih;Whh] rows 0..2047
  bf16* whn_b  = (bf16*)alloc((size_t)D * D * 2);          // 2 MB  Whh rows 2048..3071
  bf16* win_b  = (bf16*)alloc((size_t)D * D * 2);          // 2 MB  Wih rows 2048..3071
  float* brz_b = (float*)alloc((size_t)2048 * 4);
  bf16* texts_b = (bf16*)alloc((size_t)J * D * 2);         // 1 MB
  bf16* k_b    = (bf16*)alloc((size_t)J * D * 2);          // 1 MB
  bf16* vT_b   = (bf16*)alloc((size_t)D * J * 2);          // 1 MB
  bf16* xcat_b = (bf16*)alloc((size_t)M * 2048 * 2);       // 32 MB [updates | slots_bf16]
  // phase-overlapped union U (56 MB)
  char* U = alloc((size_t)56 * 1024 * 1024);
  bf16*  xln_b  = (bf16*)(U);                              // 16 MB (attn + mlp phases)
  bf16*  q_b    = (bf16*)(U + (size_t)16 * 1024 * 1024);   // 16 MB
  float* dots_f = (float*)(U + (size_t)32 * 1024 * 1024);  // 16 MB
  bf16*  attn_b = (bf16*)(U + (size_t)48 * 1024 * 1024);   // 8 MB
  bf16*  rz_b   = (bf16*)(U);                              // 32 MB (gru phase)
  bf16*  hn_b   = (bf16*)(U + (size_t)32 * 1024 * 1024);   // 16 MB
  bf16*  h1_b   = (bf16*)(U + (size_t)16 * 1024 * 1024);   // 32 MB (mlp phase)

  if (ws_size < off) return;  // fail loudly (poison absmax) instead of faulting

  float* slots_f = (float*)d_out;   // master fp32 state

  // ---- weight prep ----
  f2b<<<dim3(D * D / 1024), 256, 0, stream>>>(Wq, wq_b);
  f2b<<<dim3(D * D / 1024), 256, 0, stream>>>(Wk, wk_b);
  f2b<<<dim3(D * D / 1024), 256, 0, stream>>>(Wv, wv_b);
  f2b<<<dim3(H * D / 1024), 256, 0, stream>>>(W1, w1_b);
  f2b<<<dim3(D * H / 1024), 256, 0, stream>>>(W2, w2_b);
  f2b<<<dim3(D * D / 1024), 256, 0, stream>>>(Whh + (size_t)2048 * D, whn_b);
  f2b<<<dim3(D * D / 1024), 256, 0, stream>>>(Wih + (size_t)2048 * D, win_b);
  make_wcat<<<dim3(2048 * 1024 / 256), 256, 0, stream>>>(Wih, Whh, wcat_b);
  make_brz<<<dim3(8), 256, 0, stream>>>(bih, bhh, brz_b);

  // ---- slots init (fp32 master + bf16 mirror in Xcat right half) ----
  init_slots<<<dim3(M * D / 1024), 256, 0, stream>>>(inputs, slots_f, xcat_b + 1024);

  // ---- texts LN -> k, v (v stored transposed [D][J]) ----
  ln_rows<<<dim3(J), 256, 0, stream>>>(texts, g_in, be_in, texts_b);
  gemm_bt<64><<<dim3(J / 128, D / 64), 256, 0, stream>>>(
      texts_b, D, wk_b, D, bk, J, D, D, 1.f, 0,
      nullptr, 0, k_b, D, nullptr, 0, nullptr, nullptr, nullptr);
  gemm_bt<64><<<dim3(J / 128, D / 64), 256, 0, stream>>>(
      texts_b, D, wv_b, D, bv, J, D, D, 1.f, 0,
      nullptr, 0, nullptr, 0, vT_b, J, nullptr, nullptr, nullptr);

  for (int it = 0; it < 3; it++) {
    // q = LN(slots) @ Wq^T + bq
    ln_rows<<<dim3(M), 256, 0, stream>>>(slots_f, g_sl, be_sl, xln_b);
    gemm_bt<64><<<dim3(M / 128, D / 64), 256, 0, stream>>>(
        xln_b, D, wq_b, D, bq, M, D, D, 1.f, 0,
        nullptr, 0, q_b, D, nullptr, 0, nullptr, nullptr, nullptr);
    // dots = q @ k^T * SCALE
    gemm_bt<64><<<dim3(M / 128, J / 64), 256, 0, stream>>>(
        q_b, D, k_b, D, nullptr, M, J, D, SCALE, 0,
        dots_f, J, nullptr, 0, nullptr, 0, nullptr, nullptr, nullptr);
    softmax_slots<<<dim3(B * J / 256), 256, 0, stream>>>(dots_f);
    attn_norm<<<dim3(M), 256, 0, stream>>>(dots_f, attn_b);
    // updates = attn @ v -> Xcat left half (ld 2048)
    gemm_bt<64><<<dim3(M / 128, D / 64), 256, 0, stream>>>(
        attn_b, J, vT_b, J, nullptr, M, D, J, 1.f, 0,
        nullptr, 0, xcat_b, 2048, nullptr, 0, nullptr, nullptr, nullptr);
    // GRU: rz = sigmoid([updates|slots] @ [Wih;Whh]_rz^T + brz)
    gemm_bt<128><<<dim3(M / 128, 2048 / 128), 256, 0, stream>>>(
        xcat_b, 2048, wcat_b, 2048, brz_b, M, 2048, 2048, 1.f, F_SIGMOID,
        nullptr, 0, rz_b, 2048, nullptr, 0, nullptr, nullptr, nullptr);
    // h_n = slots @ Whh_n^T + bhh_n
    gemm_bt<64><<<dim3(M / 128, D / 64), 256, 0, stream>>>(
        xcat_b + 1024, 2048, whn_b, D, bhh + 2048, M, D, D, 1.f, 0,
        nullptr, 0, hn_b, D, nullptr, 0, nullptr, nullptr, nullptr);
    // i_n GEMM + fused GRU epilogue -> slots_f (fp32) + Xcat right half (bf16)
    gemm_bt<64><<<dim3(M / 128, D / 64), 256, 0, stream>>>(
        xcat_b, 2048, win_b, D, bih + 2048, M, D, D, 1.f, F_GRU,
        slots_f, D, xcat_b + 1024, 2048, nullptr, 0, slots_f, rz_b, hn_b);
    // MLP residual, H split into two 2048 halves
    ln_rows<<<dim3(M), 256, 0, stream>>>(slots_f, g_ff, be_ff, xln_b);
    gemm_bt<128><<<dim3(M / 128, 2048 / 128), 256, 0, stream>>>(
        xln_b, D, w1_b, D, b1, M, 2048, D, 1.f, F_RELU,
        nullptr, 0, h1_b, 2048, nullptr, 0, nullptr, nullptr, nullptr);
    gemm_bt<64><<<dim3(M / 128, D / 64), 256, 0, stream>>>(
        h1_b, 2048, w2_b, H, b2, M, D, 2048, 1.f, 0,
        slots_f, D, nullptr, 0, nullptr, 0, slots_f, nullptr, nullptr);
    gemm_bt<128><<<dim3(M / 128, 2048 / 128), 256, 0, stream>>>(
        xln_b, D, w1_b + (size_t)2048 * D, D, b1 + 2048, M, 2048, D, 1.f, F_RELU,
        nullptr, 0, h1_b, 2048, nullptr, 0, nullptr, nullptr, nullptr);
    gemm_bt<64><<<dim3(M / 128, D / 64), 256, 0, stream>>>(
        h1_b, 2048, w2_b + 2048, H, nullptr, M, D, 2048, 1.f, 0,
        slots_f, D, xcat_b + 1024, 2048, nullptr, 0, slots_f, nullptr, nullptr);
  }
}

// Round 5
// 1705.403 us; speedup vs baseline: 1.3379x; 1.0716x over previous
//
#include <hip/hip_runtime.h>
#include <hip/hip_bf16.h>
#include <stdint.h>

// SlotAttention on MI355X. GEMMs: C[M,N] = X[M,K] @ W[N,K]^T, bf16 MFMA
// 16x16x32, fp32 acc, m97 structure, __launch_bounds__(256,4) (R4: 4 blk/CU).
// R5: (a) qproj eliminated: dots = xln @ (k@Wq)^T + SCALE*<bq,k[j]> (kq, bqk
// precomputed once -- k is iter-invariant); (b) LDS-tile fused softmax (512
// blocks) emitting bf16 softmax + row partial sums; (c) attn_norm folded into
// attnV epilogue: updates = (sm@v + eps*vcol) * rowinv. Workspace ~118 MB.

using bf16 = __hip_bfloat16;
typedef __bf16 bf16x8 __attribute__((ext_vector_type(8)));
typedef float f32x4 __attribute__((ext_vector_type(4)));

#define F_RELU    1
#define F_SIGMOID 2
#define F_GRU     4
#define F_ATTNV   8

__device__ __forceinline__ void gl_to_lds16(const void* g, void* l) {
  __builtin_amdgcn_global_load_lds(
      (const __attribute__((address_space(1))) uint32_t*)(uintptr_t)g,
      (__attribute__((address_space(3))) uint32_t*)(uintptr_t)l,
      16, 0, 0);
}

// Tile: 128 x BN, 4 waves as 2x2, each wave 64 x BN/2 (4 x BN/32 MFMA frags).
template <int BN>
__global__ __launch_bounds__(256, 4) void gemm_bt(
    const bf16* __restrict__ X, int ldx,
    const bf16* __restrict__ W, int ldw,
    const float* __restrict__ bias,
    int M, int N, int K, float scale, int flags,
    float* __restrict__ outF, int ldf,
    bf16* __restrict__ outB, int ldb,
    bf16* __restrict__ outT, int ldt,
    const float* __restrict__ resid,
    const bf16* __restrict__ rz,    // F_GRU: sigmoided r|z, ld 2048
    const bf16* __restrict__ hn,    // F_GRU: h_n pre-act, ld 1024
    const float* __restrict__ auxA, // F_ATTNV: vcol[N]
    const float* __restrict__ auxB) // F_ATTNV: rowinv[M]
{
  constexpr int NJ = BN / 32;
  __shared__ __align__(16) bf16 As[128 * 32];
  __shared__ __align__(16) bf16 Bs[BN * 32];
  const int t = threadIdx.x;
  const int m0 = blockIdx.x * 128, n0 = blockIdx.y * BN;
  const int wave = t >> 6, lane = t & 63;
  const int wm = (wave >> 1) * 64, wn = (wave & 1) * (BN / 2);
  const int lrow = lane & 15, quad = lane >> 4;

  f32x4 acc[4][NJ] = {};

  const int srow = t >> 2;
  const int scol = (t & 3) * 8;
  const bf16* Ag  = X + (size_t)(m0 + srow) * ldx + scol;
  const bf16* Ag2 = Ag + (size_t)64 * ldx;
  const bf16* Bg  = W + (size_t)(n0 + srow) * ldw + scol;
  const bf16* Bg2 = Bg + (size_t)64 * ldw;   // only BN==128
  bf16* Al  = As + t * 8;   // lane-contiguous (global_load_lds rule)
  bf16* Al2 = Al + 64 * 32;
  bf16* Bl  = Bs + t * 8;
  bf16* Bl2 = Bl + 64 * 32;

  for (int k0 = 0; k0 < K; k0 += 32) {
    gl_to_lds16(Ag + k0, Al);
    gl_to_lds16(Ag2 + k0, Al2);
    gl_to_lds16(Bg + k0, Bl);
    if (BN == 128) gl_to_lds16(Bg2 + k0, Bl2);
    __syncthreads();
    bf16x8 af[4], bfr[NJ];
    const bf16x8* Asv = (const bf16x8*)As;
    const bf16x8* Bsv = (const bf16x8*)Bs;
#pragma unroll
    for (int i = 0; i < 4; i++)  af[i]  = Asv[(wm + i * 16 + lrow) * 4 + quad];
#pragma unroll
    for (int j = 0; j < NJ; j++) bfr[j] = Bsv[(wn + j * 16 + lrow) * 4 + quad];
#pragma unroll
    for (int i = 0; i < 4; i++)
#pragma unroll
      for (int j = 0; j < NJ; j++)
        acc[i][j] = __builtin_amdgcn_mfma_f32_16x16x32_bf16(af[i], bfr[j], acc[i][j], 0, 0, 0);
    __syncthreads();
  }

#pragma unroll
  for (int i = 0; i < 4; i++) {
    const int row0 = m0 + wm + i * 16 + quad * 4;
#pragma unroll
    for (int j = 0; j < NJ; j++) {
      const int col = n0 + wn + j * 16 + lrow;
      const float badd = bias ? bias[col] : 0.f;
#pragma unroll
      for (int r = 0; r < 4; r++) {
        const int row = row0 + r;
        float val = acc[i][j][r] * scale + badd;
        if (flags & F_RELU)    val = fmaxf(val, 0.f);
        if (flags & F_SIGMOID) val = 1.f / (1.f + expf(-val));
        if (flags & F_ATTNV)   val = (val + 1e-8f * auxA[col]) * auxB[row];
        if (flags & F_GRU) {
          const size_t ridx = (size_t)row * 1024 + col;
          const float rg = __bfloat162float(rz[(size_t)row * 2048 + col]);
          const float zg = __bfloat162float(rz[(size_t)row * 2048 + 1024 + col]);
          const float hv = __bfloat162float(hn[ridx]);
          const float ng = tanhf(val + rg * hv);
          const float prev = resid[ridx];
          val = (1.f - zg) * ng + zg * prev;
        } else if (resid) {
          val += resid[(size_t)row * ldf + col];
        }
        if (outF) outF[(size_t)row * ldf + col] = val;
        if (outB) outB[(size_t)row * ldb + col] = __float2bfloat16(val);
        if (outT) outT[(size_t)col * ldt + row] = __float2bfloat16(val);
      }
    }
  }
}

// LayerNorm over D=1024, one block per row, bf16 out.
__global__ __launch_bounds__(256) void ln_rows(const float* __restrict__ x,
    const float* __restrict__ g, const float* __restrict__ b,
    bf16* __restrict__ out)
{
  const int row = blockIdx.x;
  const int t = threadIdx.x;
  const float* xr = x + (size_t)row * 1024;
  float v[4];
  float s = 0.f, s2 = 0.f;
#pragma unroll
  for (int i = 0; i < 4; i++) {
    float val = xr[t + 256 * i];
    v[i] = val; s += val; s2 += val * val;
  }
#pragma unroll
  for (int off = 32; off > 0; off >>= 1) {
    s  += __shfl_down(s, off);
    s2 += __shfl_down(s2, off);
  }
  __shared__ float rs[4], rs2[4];
  if ((t & 63) == 0) { rs[t >> 6] = s; rs2[t >> 6] = s2; }
  __syncthreads();
  const float S  = rs[0] + rs[1] + rs[2] + rs[3];
  const float S2 = rs2[0] + rs2[1] + rs2[2] + rs2[3];
  const float mean = S * (1.f / 1024.f);
  const float var  = S2 * (1.f / 1024.f) - mean * mean;
  const float rstd = rsqrtf(var + 1e-5f);
  bf16* outr = out + (size_t)row * 1024;
#pragma unroll
  for (int i = 0; i < 4; i++) {
    const int c = t + 256 * i;
    outr[c] = __float2bfloat16((v[i] - mean) * rstd * g[c] + b[c]);
  }
}

// Fused softmax over slots axis i of dots[b][i][j] (i=128), per (b, 64-j tile).
// Writes bf16 softmax + per-tile row partial sums P[m][8].
__global__ __launch_bounds__(256) void softmax_fused(
    const float* __restrict__ dots, bf16* __restrict__ sm,
    float* __restrict__ P)
{
  __shared__ float tile[128][65];
  __shared__ float cred[4][64];
  __shared__ float colmax[64], colinv[64];
  const int b = blockIdx.x, jt = blockIdx.y;
  const int t = threadIdx.x;
  const float* src = dots + (size_t)b * (128 * 512) + jt * 64;
  // load 128x64 tile (4 rows per pass)
#pragma unroll
  for (int p = 0; p < 32; p++) {
    const int i = p * 4 + (t >> 6), c = t & 63;
    tile[i][c] = src[(size_t)i * 512 + c];
  }
  __syncthreads();
  const int c = t & 63, s = t >> 6;
  // column max (4-way split over i)
  float mx = -1e30f;
  for (int i = s * 32; i < s * 32 + 32; i++) mx = fmaxf(mx, tile[i][c]);
  cred[s][c] = mx;
  __syncthreads();
  if (s == 0) colmax[c] = fmaxf(fmaxf(cred[0][c], cred[1][c]),
                                fmaxf(cred[2][c], cred[3][c]));
  __syncthreads();
  // exp + column sum
  const float cm = colmax[c];
  float sum = 0.f;
  for (int i = s * 32; i < s * 32 + 32; i++) {
    const float e = expf(tile[i][c] - cm);
    tile[i][c] = e; sum += e;
  }
  cred[s][c] = sum;
  __syncthreads();
  if (s == 0) colinv[c] = 1.f / (cred[0][c] + cred[1][c] + cred[2][c] + cred[3][c]);
  __syncthreads();
  // write normalized bf16
  bf16* dst = sm + (size_t)b * (128 * 512) + jt * 64;
#pragma unroll
  for (int p = 0; p < 32; p++) {
    const int i = p * 4 + (t >> 6), cc = t & 63;
    dst[(size_t)i * 512 + cc] = __float2bfloat16(tile[i][cc] * colinv[cc]);
  }
  // row partial sums (threads 0..127)
  if (t < 128) {
    float rs = 0.f;
    for (int cc = 0; cc < 64; cc++) rs += tile[t][cc] * colinv[cc];
    P[((size_t)b * 128 + t) * 8 + jt] = rs;
  }
}

// rowinv[m] = 1 / (sum_jt P[m][jt] + 512e-8)
__global__ __launch_bounds__(256) void rowinv_k(const float* __restrict__ P,
                                                float* __restrict__ rowinv)
{
  const int m = blockIdx.x * 256 + threadIdx.x;
  const float* p = P + (size_t)m * 8;
  float s = 0.f;
#pragma unroll
  for (int i = 0; i < 8; i++) s += p[i];
  rowinv[m] = 1.f / (s + 512.f * 1e-8f);
}

// slots init: fp32 master + bf16 mirror into Xcat right half (ld 2048).
__global__ __launch_bounds__(256) void init_slots(const float* __restrict__ x,
    float* __restrict__ sf, bf16* __restrict__ xr)
{
  const size_t base = (size_t)blockIdx.x * 1024 + threadIdx.x;
#pragma unroll
  for (int i = 0; i < 4; i++) {
    const size_t idx = base + 256 * i;
    const float v = x[idx];
    sf[idx] = v;
    xr[(idx >> 10) * 2048 + (idx & 1023)] = __float2bfloat16(v);
  }
}

__global__ __launch_bounds__(256) void f2b(const float* __restrict__ x,
                                           bf16* __restrict__ y)
{
  const size_t base = (size_t)blockIdx.x * 1024 + threadIdx.x;
#pragma unroll
  for (int i = 0; i < 4; i++) y[base + 256 * i] = __float2bfloat16(x[base + 256 * i]);
}

// wqT[d][d'] = Wq[d'][d]
__global__ __launch_bounds__(256) void f2b_T(const float* __restrict__ Wq,
                                             bf16* __restrict__ wqT)
{
  const int idx = blockIdx.x * 256 + threadIdx.x;  // 1024*1024
  const int d = idx >> 10, dp = idx & 1023;
  wqT[idx] = __float2bfloat16(Wq[(size_t)dp * 1024 + d]);
}

// wcat[n][0:1024]=Wih[n], wcat[n][1024:2048]=Whh[n]  (n in [0,2048))
__global__ __launch_bounds__(256) void make_wcat(const float* __restrict__ Wih,
    const float* __restrict__ Whh, bf16* __restrict__ wcat)
{
  const int idx = blockIdx.x * 256 + threadIdx.x;
  const int n = idx >> 10, c = idx & 1023;
  wcat[(size_t)n * 2048 + c]        = __float2bfloat16(Wih[(size_t)n * 1024 + c]);
  wcat[(size_t)n * 2048 + 1024 + c] = __float2bfloat16(Whh[(size_t)n * 1024 + c]);
}

__global__ __launch_bounds__(256) void make_brz(const float* __restrict__ bih,
    const float* __restrict__ bhh, float* __restrict__ brz)
{
  const int n = blockIdx.x * 256 + threadIdx.x;
  brz[n] = bih[n] + bhh[n];
}

// bqk[j] = SCALE * <bq, k[j,:]>   (k bf16 [512,1024])
__global__ __launch_bounds__(256) void make_bqk(const bf16* __restrict__ k,
    const float* __restrict__ bq, float* __restrict__ bqk, float scale)
{
  const int j = blockIdx.x * 256 + threadIdx.x;  // 512
  const bf16* kr = k + (size_t)j * 1024;
  float s = 0.f;
  for (int d = 0; d < 1024; d++) s += bq[d] * __bfloat162float(kr[d]);
  bqk[j] = scale * s;
}

// vcol[d] = sum_j v[j,d] = row-sum of vT[d][j]
__global__ __launch_bounds__(256) void make_vcol(const bf16* __restrict__ vT,
                                                 float* __restrict__ vcol)
{
  const int d = blockIdx.x * 256 + threadIdx.x;  // 1024
  const bf16* r = vT + (size_t)d * 512;
  float s = 0.f;
  for (int j = 0; j < 512; j++) s += __bfloat162float(r[j]);
  vcol[d] = s;
}

extern "C" void kernel_launch(void* const* d_in, const int* in_sizes, int n_in,
                              void* d_out, int out_size, void* d_ws, size_t ws_size,
                              hipStream_t stream)
{
  const float* inputs = (const float*)d_in[0];
  const float* texts  = (const float*)d_in[1];
  const float* Wq  = (const float*)d_in[2];  const float* bq  = (const float*)d_in[3];
  const float* Wk  = (const float*)d_in[4];  const float* bk  = (const float*)d_in[5];
  const float* Wv  = (const float*)d_in[6];  const float* bv  = (const float*)d_in[7];
  const float* Wih = (const float*)d_in[8];  const float* bih = (const float*)d_in[9];
  const float* Whh = (const float*)d_in[10]; const float* bhh = (const float*)d_in[11];
  const float* W1  = (const float*)d_in[12]; const float* b1  = (const float*)d_in[13];
  const float* W2  = (const float*)d_in[14]; const float* b2  = (const float*)d_in[15];
  const float* g_in = (const float*)d_in[16]; const float* be_in = (const float*)d_in[17];
  const float* g_sl = (const float*)d_in[18]; const float* be_sl = (const float*)d_in[19];
  const float* g_ff = (const float*)d_in[20]; const float* be_ff = (const float*)d_in[21];

  constexpr int B = 64, N = 128, J = 512, D = 1024, H = 4096;
  constexpr int M = B * N;
  const float SCALE = 0.03125f;

  char* ws = (char*)d_ws;
  size_t off = 0;
  auto alloc = [&](size_t bytes) -> char* {
    char* p = ws + off; off += (bytes + 255) & ~(size_t)255; return p;
  };
  // persistent (~70.3 MB)
  bf16* wk_b   = (bf16*)alloc((size_t)D * D * 2);
  bf16* wv_b   = (bf16*)alloc((size_t)D * D * 2);
  bf16* w1_b   = (bf16*)alloc((size_t)H * D * 2);
  bf16* w2_b   = (bf16*)alloc((size_t)D * H * 2);
  bf16* wcat_b = (bf16*)alloc((size_t)2048 * 2048 * 2);
  bf16* whn_b  = (bf16*)alloc((size_t)D * D * 2);
  bf16* win_b  = (bf16*)alloc((size_t)D * D * 2);
  bf16* wqT_b  = (bf16*)alloc((size_t)D * D * 2);
  bf16* kq_b   = (bf16*)alloc((size_t)J * D * 2);
  bf16* texts_n = (bf16*)alloc((size_t)J * D * 2);
  bf16* k_b    = (bf16*)alloc((size_t)J * D * 2);
  bf16* vT_b   = (bf16*)alloc((size_t)D * J * 2);
  bf16* xcat_b = (bf16*)alloc((size_t)M * 2048 * 2);       // 32 MB [updates|slots]
  float* brz_b = (float*)alloc((size_t)2048 * 4);
  float* bqk_b = (float*)alloc((size_t)J * 4);
  float* vcol_b = (float*)alloc((size_t)D * 4);
  float* P_b   = (float*)alloc((size_t)M * 8 * 4);
  float* rinv_b = (float*)alloc((size_t)M * 4);
  // phase-overlapped union U (48 MB)
  char* U = alloc((size_t)48 * 1024 * 1024);
  bf16*  xln_b  = (bf16*)(U);                              // 16 MB (attn+mlp)
  float* dots_f = (float*)(U + (size_t)16 * 1024 * 1024);  // 16 MB
  bf16*  sm_b   = (bf16*)(U + (size_t)32 * 1024 * 1024);   // 8 MB
  bf16*  rz_b   = (bf16*)(U);                              // 32 MB (gru)
  bf16*  hn_b   = (bf16*)(U + (size_t)32 * 1024 * 1024);   // 16 MB (gru)
  bf16*  h1_b   = (bf16*)(U + (size_t)16 * 1024 * 1024);   // 32 MB (mlp)

  if (ws_size < off) return;  // fail loudly instead of faulting

  float* slots_f = (float*)d_out;

  // ---- weight prep ----
  f2b<<<dim3(D * D / 1024), 256, 0, stream>>>(Wk, wk_b);
  f2b<<<dim3(D * D / 1024), 256, 0, stream>>>(Wv, wv_b);
  f2b<<<dim3(H * D / 1024), 256, 0, stream>>>(W1, w1_b);
  f2b<<<dim3(D * H / 1024), 256, 0, stream>>>(W2, w2_b);
  f2b<<<dim3(D * D / 1024), 256, 0, stream>>>(Whh + (size_t)2048 * D, whn_b);
  f2b<<<dim3(D * D / 1024), 256, 0, stream>>>(Wih + (size_t)2048 * D, win_b);
  f2b_T<<<dim3(D * D / 256), 256, 0, stream>>>(Wq, wqT_b);
  make_wcat<<<dim3(2048 * 1024 / 256), 256, 0, stream>>>(Wih, Whh, wcat_b);
  make_brz<<<dim3(8), 256, 0, stream>>>(bih, bhh, brz_b);

  init_slots<<<dim3(M * D / 1024), 256, 0, stream>>>(inputs, slots_f, xcat_b + 1024);

  // ---- iteration-invariant attention tensors ----
  ln_rows<<<dim3(J), 256, 0, stream>>>(texts, g_in, be_in, texts_n);
  // k = LN(texts) @ Wk^T + bk
  gemm_bt<64><<<dim3(J / 128, D / 64), 256, 0, stream>>>(
      texts_n, D, wk_b, D, bk, J, D, D, 1.f, 0,
      nullptr, 0, k_b, D, nullptr, 0, nullptr, nullptr, nullptr, nullptr, nullptr);
  // vT = (LN(texts) @ Wv^T + bv)^T
  gemm_bt<64><<<dim3(J / 128, D / 64), 256, 0, stream>>>(
      texts_n, D, wv_b, D, bv, J, D, D, 1.f, 0,
      nullptr, 0, nullptr, 0, vT_b, J, nullptr, nullptr, nullptr, nullptr, nullptr);
  // kq = k @ Wq  (X@W^T with W = Wq^T)
  gemm_bt<64><<<dim3(J / 128, D / 64), 256, 0, stream>>>(
      k_b, D, wqT_b, D, nullptr, J, D, D, 1.f, 0,
      nullptr, 0, kq_b, D, nullptr, 0, nullptr, nullptr, nullptr, nullptr, nullptr);
  make_bqk<<<dim3(2), 256, 0, stream>>>(k_b, bq, bqk_b, SCALE);
  make_vcol<<<dim3(4), 256, 0, stream>>>(vT_b, vcol_b);

  for (int it = 0; it < 3; it++) {
    // xln = LN(slots)
    ln_rows<<<dim3(M), 256, 0, stream>>>(slots_f, g_sl, be_sl, xln_b);
    // dots = SCALE*(xln @ kq^T) + bqk
    gemm_bt<64><<<dim3(M / 128, J / 64), 256, 0, stream>>>(
        xln_b, D, kq_b, D, bqk_b, M, J, D, SCALE, 0,
        dots_f, J, nullptr, 0, nullptr, 0, nullptr, nullptr, nullptr, nullptr, nullptr);
    // softmax over slots axis + row partials; then rowinv
    softmax_fused<<<dim3(B, 8), 256, 0, stream>>>(dots_f, sm_b, P_b);
    rowinv_k<<<dim3(M / 256), 256, 0, stream>>>(P_b, rinv_b);
    // updates = (sm @ v + eps*vcol) * rowinv -> Xcat left half
    gemm_bt<64><<<dim3(M / 128, D / 64), 256, 0, stream>>>(
        sm_b, J, vT_b, J, nullptr, M, D, J, 1.f, F_ATTNV,
        nullptr, 0, xcat_b, 2048, nullptr, 0, nullptr, nullptr, nullptr,
        vcol_b, rinv_b);
    // GRU: rz = sigmoid([updates|slots] @ [Wih;Whh]_rz^T + brz)
    gemm_bt<128><<<dim3(M / 128, 2048 / 128), 256, 0, stream>>>(
        xcat_b, 2048, wcat_b, 2048, brz_b, M, 2048, 2048, 1.f, F_SIGMOID,
        nullptr, 0, rz_b, 2048, nullptr, 0, nullptr, nullptr, nullptr, nullptr, nullptr);
    // h_n = slots @ Whh_n^T + bhh_n
    gemm_bt<64><<<dim3(M / 128, D / 64), 256, 0, stream>>>(
        xcat_b + 1024, 2048, whn_b, D, bhh + 2048, M, D, D, 1.f, 0,
        nullptr, 0, hn_b, D, nullptr, 0, nullptr, nullptr, nullptr, nullptr, nullptr);
    // i_n GEMM + fused GRU epilogue -> slots_f + Xcat right half
    gemm_bt<64><<<dim3(M / 128, D / 64), 256, 0, stream>>>(
        xcat_b, 2048, win_b, D, bih + 2048, M, D, D, 1.f, F_GRU,
        slots_f, D, xcat_b + 1024, 2048, nullptr, 0, slots_f, rz_b, hn_b,
        nullptr, nullptr);
    // MLP residual, H split into two 2048 halves
    ln_rows<<<dim3(M), 256, 0, stream>>>(slots_f, g_ff, be_ff, xln_b);
    gemm_bt<128><<<dim3(M / 128, 2048 / 128), 256, 0, stream>>>(
        xln_b, D, w1_b, D, b1, M, 2048, D, 1.f, F_RELU,
        nullptr, 0, h1_b, 2048, nullptr, 0, nullptr, nullptr, nullptr, nullptr, nullptr);
    gemm_bt<64><<<dim3(M / 128, D / 64), 256, 0, stream>>>(
        h1_b, 2048, w2_b, H, b2, M, D, 2048, 1.f, 0,
        slots_f, D, nullptr, 0, nullptr, 0, slots_f, nullptr, nullptr, nullptr, nullptr);
    gemm_bt<128><<<dim3(M / 128, 2048 / 128), 256, 0, stream>>>(
        xln_b, D, w1_b + (size_t)2048 * D, D, b1 + 2048, M, 2048, D, 1.f, F_RELU,
        nullptr, 0, h1_b, 2048, nullptr, 0, nullptr, nullptr, nullptr, nullptr, nullptr);
    gemm_bt<64><<<dim3(M / 128, D / 64), 256, 0, stream>>>(
        h1_b, 2048, w2_b + 2048, H, nullptr, M, D, 2048, 1.f, 0,
        slots_f, D, xcat_b + 1024, 2048, nullptr, 0, slots_f, nullptr, nullptr,
        nullptr, nullptr);
  }
}

// Round 7
// 1659.321 us; speedup vs baseline: 1.3750x; 1.0278x over previous
//
#include <hip/hip_runtime.h>
#include <hip/hip_bf16.h>
#include <stdint.h>

// SlotAttention on MI355X. GEMMs: C[M,N] = X[M,K] @ W[N,K]^T, bf16 MFMA
// 16x16x32, fp32 acc, m97 structure, __launch_bounds__(256,4).
// R7 = R6 with the dots call-site arg-count bug fixed (18->19 args).
// R6: attn.V folded into GRU gates algebraically. v is iter-invariant, and
// updates only feeds gi = updates@Wih^T. With PT = Wih@v^T (precomputed once),
// gi = (rowinv*sm)@PT^T + eps*rowinv[m]*c[n] + b_ih, c = Wih@vcol.
//  - attnV GEMM eliminated (updates never materialized)
//  - rz concat GEMM: [sm2|slots]@[PT_rz;Whh_rz]^T, K=1536 (was 2048)
//  - i_n GEMM: K=512 (was 1024)
// Workspace ~113 MB (proven-safe band).

using bf16 = __hip_bfloat16;
typedef __bf16 bf16x8 __attribute__((ext_vector_type(8)));
typedef float f32x4 __attribute__((ext_vector_type(4)));

#define F_RELU    1
#define F_SIGMOID 2
#define F_GRU     4
#define F_EPSC    8

__device__ __forceinline__ void gl_to_lds16(const void* g, void* l) {
  __builtin_amdgcn_global_load_lds(
      (const __attribute__((address_space(1))) uint32_t*)(uintptr_t)g,
      (__attribute__((address_space(3))) uint32_t*)(uintptr_t)l,
      16, 0, 0);
}

// Tile: 128 x BN, 4 waves as 2x2, each wave 64 x BN/2 (4 x BN/32 MFMA frags).
template <int BN>
__global__ __launch_bounds__(256, 4) void gemm_bt(
    const bf16* __restrict__ X, int ldx,
    const bf16* __restrict__ W, int ldw,
    const float* __restrict__ bias,
    int M, int N, int K, float scale, int flags,
    float* __restrict__ outF, int ldf,
    bf16* __restrict__ outB, int ldb,
    const float* __restrict__ resid,
    const bf16* __restrict__ rz,    // F_GRU: sigmoided r|z, ld 2048
    const bf16* __restrict__ hn,    // F_GRU: h_n pre-act, ld 1024
    const float* __restrict__ auxA, // F_EPSC: c[col]
    const float* __restrict__ auxB) // F_EPSC: rowinv[row]
{
  constexpr int NJ = BN / 32;
  __shared__ __align__(16) bf16 As[128 * 32];
  __shared__ __align__(16) bf16 Bs[BN * 32];
  const int t = threadIdx.x;
  const int m0 = blockIdx.x * 128, n0 = blockIdx.y * BN;
  const int wave = t >> 6, lane = t & 63;
  const int wm = (wave >> 1) * 64, wn = (wave & 1) * (BN / 2);
  const int lrow = lane & 15, quad = lane >> 4;

  f32x4 acc[4][NJ] = {};

  const int srow = t >> 2;
  const int scol = (t & 3) * 8;
  const bf16* Ag  = X + (size_t)(m0 + srow) * ldx + scol;
  const bf16* Ag2 = Ag + (size_t)64 * ldx;
  const bf16* Bg  = W + (size_t)(n0 + srow) * ldw + scol;
  const bf16* Bg2 = Bg + (size_t)64 * ldw;   // only BN==128
  bf16* Al  = As + t * 8;   // lane-contiguous (global_load_lds rule)
  bf16* Al2 = Al + 64 * 32;
  bf16* Bl  = Bs + t * 8;
  bf16* Bl2 = Bl + 64 * 32;

  for (int k0 = 0; k0 < K; k0 += 32) {
    gl_to_lds16(Ag + k0, Al);
    gl_to_lds16(Ag2 + k0, Al2);
    gl_to_lds16(Bg + k0, Bl);
    if (BN == 128) gl_to_lds16(Bg2 + k0, Bl2);
    __syncthreads();
    bf16x8 af[4], bfr[NJ];
    const bf16x8* Asv = (const bf16x8*)As;
    const bf16x8* Bsv = (const bf16x8*)Bs;
#pragma unroll
    for (int i = 0; i < 4; i++)  af[i]  = Asv[(wm + i * 16 + lrow) * 4 + quad];
#pragma unroll
    for (int j = 0; j < NJ; j++) bfr[j] = Bsv[(wn + j * 16 + lrow) * 4 + quad];
#pragma unroll
    for (int i = 0; i < 4; i++)
#pragma unroll
      for (int j = 0; j < NJ; j++)
        acc[i][j] = __builtin_amdgcn_mfma_f32_16x16x32_bf16(af[i], bfr[j], acc[i][j], 0, 0, 0);
    __syncthreads();
  }

#pragma unroll
  for (int i = 0; i < 4; i++) {
    const int row0 = m0 + wm + i * 16 + quad * 4;
#pragma unroll
    for (int j = 0; j < NJ; j++) {
      const int col = n0 + wn + j * 16 + lrow;
      const float badd = bias ? bias[col] : 0.f;
#pragma unroll
      for (int r = 0; r < 4; r++) {
        const int row = row0 + r;
        float val = acc[i][j][r] * scale + badd;
        if (flags & F_EPSC)    val += 1e-8f * auxA[col] * auxB[row];
        if (flags & F_RELU)    val = fmaxf(val, 0.f);
        if (flags & F_SIGMOID) val = 1.f / (1.f + expf(-val));
        if (flags & F_GRU) {
          const size_t ridx = (size_t)row * 1024 + col;
          const float rg = __bfloat162float(rz[(size_t)row * 2048 + col]);
          const float zg = __bfloat162float(rz[(size_t)row * 2048 + 1024 + col]);
          const float hv = __bfloat162float(hn[ridx]);
          const float ng = tanhf(val + rg * hv);
          const float prev = resid[ridx];
          val = (1.f - zg) * ng + zg * prev;
        } else if (resid) {
          val += resid[(size_t)row * ldf + col];
        }
        if (outF) outF[(size_t)row * ldf + col] = val;
        if (outB) outB[(size_t)row * ldb + col] = __float2bfloat16(val);
      }
    }
  }
}

// LayerNorm over D=1024, one block per row, bf16 out (stride ldo).
__global__ __launch_bounds__(256) void ln_rows(const float* __restrict__ x,
    const float* __restrict__ g, const float* __restrict__ b,
    bf16* __restrict__ out, int ldo)
{
  const int row = blockIdx.x;
  const int t = threadIdx.x;
  const float* xr = x + (size_t)row * 1024;
  float v[4];
  float s = 0.f, s2 = 0.f;
#pragma unroll
  for (int i = 0; i < 4; i++) {
    float val = xr[t + 256 * i];
    v[i] = val; s += val; s2 += val * val;
  }
#pragma unroll
  for (int off = 32; off > 0; off >>= 1) {
    s  += __shfl_down(s, off);
    s2 += __shfl_down(s2, off);
  }
  __shared__ float rs[4], rs2[4];
  if ((t & 63) == 0) { rs[t >> 6] = s; rs2[t >> 6] = s2; }
  __syncthreads();
  const float S  = rs[0] + rs[1] + rs[2] + rs[3];
  const float S2 = rs2[0] + rs2[1] + rs2[2] + rs2[3];
  const float mean = S * (1.f / 1024.f);
  const float var  = S2 * (1.f / 1024.f) - mean * mean;
  const float rstd = rsqrtf(var + 1e-5f);
  bf16* outr = out + (size_t)row * ldo;
#pragma unroll
  for (int i = 0; i < 4; i++) {
    const int c = t + 256 * i;
    outr[c] = __float2bfloat16((v[i] - mean) * rstd * g[c] + b[c]);
  }
}

// Fused softmax over slots axis i of dots[b][i][j] (i=128), per (b, 64-j tile).
// Writes bf16 softmax into xcat2 cols [0,512) (ld 1536) + row partials P[m][8].
__global__ __launch_bounds__(256) void softmax_fused(
    const float* __restrict__ dots, bf16* __restrict__ xcat2,
    float* __restrict__ P)
{
  __shared__ float tile[128][65];
  __shared__ float cred[4][64];
  __shared__ float colmax[64], colinv[64];
  const int b = blockIdx.x, jt = blockIdx.y;
  const int t = threadIdx.x;
  const float* src = dots + (size_t)b * (128 * 512) + jt * 64;
#pragma unroll
  for (int p = 0; p < 32; p++) {
    const int i = p * 4 + (t >> 6), c = t & 63;
    tile[i][c] = src[(size_t)i * 512 + c];
  }
  __syncthreads();
  const int c = t & 63, s = t >> 6;
  float mx = -1e30f;
  for (int i = s * 32; i < s * 32 + 32; i++) mx = fmaxf(mx, tile[i][c]);
  cred[s][c] = mx;
  __syncthreads();
  if (s == 0) colmax[c] = fmaxf(fmaxf(cred[0][c], cred[1][c]),
                                fmaxf(cred[2][c], cred[3][c]));
  __syncthreads();
  const float cm = colmax[c];
  float sum = 0.f;
  for (int i = s * 32; i < s * 32 + 32; i++) {
    const float e = expf(tile[i][c] - cm);
    tile[i][c] = e; sum += e;
  }
  cred[s][c] = sum;
  __syncthreads();
  if (s == 0) colinv[c] = 1.f / (cred[0][c] + cred[1][c] + cred[2][c] + cred[3][c]);
  __syncthreads();
  bf16* dst = xcat2 + (size_t)b * 128 * 1536 + jt * 64;
#pragma unroll
  for (int p = 0; p < 32; p++) {
    const int i = p * 4 + (t >> 6), cc = t & 63;
    dst[(size_t)i * 1536 + cc] = __float2bfloat16(tile[i][cc] * colinv[cc]);
  }
  if (t < 128) {
    float rs = 0.f;
    for (int cc = 0; cc < 64; cc++) rs += tile[t][cc] * colinv[cc];
    P[((size_t)b * 128 + t) * 8 + jt] = rs;
  }
}

// rowinv[m] = 1 / (sum_jt P[m][jt] + 512e-8)
__global__ __launch_bounds__(256) void rowinv_k(const float* __restrict__ P,
                                                float* __restrict__ rowinv)
{
  const int m = blockIdx.x * 256 + threadIdx.x;
  const float* p = P + (size_t)m * 8;
  float s = 0.f;
#pragma unroll
  for (int i = 0; i < 8; i++) s += p[i];
  rowinv[m] = 1.f / (s + 512.f * 1e-8f);
}

// xcat2 sm-columns *= rowinv[m]  (in-place, cols [0,512))
__global__ __launch_bounds__(256) void smscale(bf16* __restrict__ x,
                                               const float* __restrict__ rinv)
{
  const int idx = blockIdx.x * 256 + threadIdx.x;  // M*512
  const int m = idx >> 9, j = idx & 511;
  const size_t a = (size_t)m * 1536 + j;
  x[a] = __float2bfloat16(__bfloat162float(x[a]) * rinv[m]);
}

// slots init: fp32 master + bf16 mirror into xcat2 cols [512,1536).
__global__ __launch_bounds__(256) void init_slots(const float* __restrict__ x,
    float* __restrict__ sf, bf16* __restrict__ xr)
{
  const size_t base = (size_t)blockIdx.x * 1024 + threadIdx.x;
#pragma unroll
  for (int i = 0; i < 4; i++) {
    const size_t idx = base + 256 * i;
    const float v = x[idx];
    sf[idx] = v;
    xr[(idx >> 10) * 1536 + (idx & 1023)] = __float2bfloat16(v);
  }
}

__global__ __launch_bounds__(256) void f2b(const float* __restrict__ x,
                                           bf16* __restrict__ y)
{
  const size_t base = (size_t)blockIdx.x * 1024 + threadIdx.x;
#pragma unroll
  for (int i = 0; i < 4; i++) y[base + 256 * i] = __float2bfloat16(x[base + 256 * i]);
}

// strided f2b: dst[n*dstld + c] = src[n*1024 + c]  (n rows x 1024 cols)
__global__ __launch_bounds__(256) void f2b_ld(const float* __restrict__ src,
                                              bf16* __restrict__ dst, int dstld)
{
  const int idx = blockIdx.x * 256 + threadIdx.x;
  const int n = idx >> 10, c = idx & 1023;
  dst[(size_t)n * dstld + c] = __float2bfloat16(src[(size_t)n * 1024 + c]);
}

// wqT[d][d'] = Wq[d'][d]
__global__ __launch_bounds__(256) void f2b_T(const float* __restrict__ Wq,
                                             bf16* __restrict__ wqT)
{
  const int idx = blockIdx.x * 256 + threadIdx.x;
  const int d = idx >> 10, dp = idx & 1023;
  wqT[idx] = __float2bfloat16(Wq[(size_t)dp * 1024 + d]);
}

__global__ __launch_bounds__(256) void make_brz(const float* __restrict__ bih,
    const float* __restrict__ bhh, float* __restrict__ brz)
{
  const int n = blockIdx.x * 256 + threadIdx.x;
  brz[n] = bih[n] + bhh[n];
}

// bqk[j] = SCALE * <bq, k[j,:]>
__global__ __launch_bounds__(256) void make_bqk(const bf16* __restrict__ k,
    const float* __restrict__ bq, float* __restrict__ bqk, float scale)
{
  const int j = blockIdx.x * 256 + threadIdx.x;
  const bf16* kr = k + (size_t)j * 1024;
  float s = 0.f;
  for (int d = 0; d < 1024; d++) s += bq[d] * __bfloat162float(kr[d]);
  bqk[j] = scale * s;
}

// vcol[d] = sum_j v[j,d]   (v row-major [512][1024])
__global__ __launch_bounds__(256) void make_vcol(const bf16* __restrict__ v,
                                                 float* __restrict__ vcol)
{
  const int d = blockIdx.x * 256 + threadIdx.x;  // 1024
  float s = 0.f;
  for (int j = 0; j < 512; j++) s += __bfloat162float(v[(size_t)j * 1024 + d]);
  vcol[d] = s;
}

// c[n] = sum_d Wih[n,d] * vcol[d]  (block per n, 3072 blocks)
__global__ __launch_bounds__(256) void make_c(const float* __restrict__ Wih,
    const float* __restrict__ vcol, float* __restrict__ c)
{
  const int n = blockIdx.x;
  const int t = threadIdx.x;
  const float* wr = Wih + (size_t)n * 1024;
  float s = 0.f;
#pragma unroll
  for (int i = 0; i < 4; i++) s += wr[t + 256 * i] * vcol[t + 256 * i];
#pragma unroll
  for (int off = 32; off > 0; off >>= 1) s += __shfl_down(s, off);
  __shared__ float rs[4];
  if ((t & 63) == 0) rs[t >> 6] = s;
  __syncthreads();
  if (t == 0) c[n] = rs[0] + rs[1] + rs[2] + rs[3];
}

extern "C" void kernel_launch(void* const* d_in, const int* in_sizes, int n_in,
                              void* d_out, int out_size, void* d_ws, size_t ws_size,
                              hipStream_t stream)
{
  const float* inputs = (const float*)d_in[0];
  const float* texts  = (const float*)d_in[1];
  const float* Wq  = (const float*)d_in[2];  const float* bq  = (const float*)d_in[3];
  const float* Wk  = (const float*)d_in[4];  const float* bk  = (const float*)d_in[5];
  const float* Wv  = (const float*)d_in[6];  const float* bv  = (const float*)d_in[7];
  const float* Wih = (const float*)d_in[8];  const float* bih = (const float*)d_in[9];
  const float* Whh = (const float*)d_in[10]; const float* bhh = (const float*)d_in[11];
  const float* W1  = (const float*)d_in[12]; const float* b1  = (const float*)d_in[13];
  const float* W2  = (const float*)d_in[14]; const float* b2  = (const float*)d_in[15];
  const float* g_in = (const float*)d_in[16]; const float* be_in = (const float*)d_in[17];
  const float* g_sl = (const float*)d_in[18]; const float* be_sl = (const float*)d_in[19];
  const float* g_ff = (const float*)d_in[20]; const float* be_ff = (const float*)d_in[21];

  constexpr int B = 64, N = 128, J = 512, D = 1024, H = 4096;
  constexpr int M = B * N;
  const float SCALE = 0.03125f;

  char* ws = (char*)d_ws;
  size_t off = 0;
  auto alloc = [&](size_t bytes) -> char* {
    char* p = ws + off; off += (bytes + 255) & ~(size_t)255; return p;
  };
  // persistent (~65 MB)
  bf16* wk_b    = (bf16*)alloc((size_t)D * D * 2);         // 2 MB
  bf16* wv_b    = (bf16*)alloc((size_t)D * D * 2);         // 2 MB
  bf16* w1_b    = (bf16*)alloc((size_t)H * D * 2);         // 8 MB
  bf16* w2_b    = (bf16*)alloc((size_t)D * H * 2);         // 8 MB
  bf16* whn_b   = (bf16*)alloc((size_t)D * D * 2);         // 2 MB Whh rows 2048:3071
  bf16* win_b   = (bf16*)alloc((size_t)D * D * 2);         // 2 MB Wih rows 2048:3071
  bf16* wihrz_b = (bf16*)alloc((size_t)2048 * D * 2);      // 4 MB Wih rows 0:2047
  bf16* wqT_b   = (bf16*)alloc((size_t)D * D * 2);         // 2 MB
  bf16* wcat2_b = (bf16*)alloc((size_t)2048 * 1536 * 2);   // 6 MB [PT_rz|Whh_rz]
  bf16* ptn_b   = (bf16*)alloc((size_t)D * J * 2);         // 1 MB PT rows 2048:3071
  bf16* kq_b    = (bf16*)alloc((size_t)J * D * 2);         // 1 MB
  bf16* texts_n = (bf16*)alloc((size_t)J * D * 2);         // 1 MB
  bf16* k_b     = (bf16*)alloc((size_t)J * D * 2);         // 1 MB
  bf16* v_b     = (bf16*)alloc((size_t)J * D * 2);         // 1 MB
  bf16* xcat2_b = (bf16*)alloc((size_t)M * 1536 * 2);      // 24 MB [sm|slots]
  float* brz_b  = (float*)alloc((size_t)2048 * 4);
  float* bqk_b  = (float*)alloc((size_t)J * 4);
  float* vcol_b = (float*)alloc((size_t)D * 4);
  float* c_b    = (float*)alloc((size_t)3072 * 4);
  float* P_b    = (float*)alloc((size_t)M * 8 * 4);
  float* rinv_b = (float*)alloc((size_t)M * 4);
  // phase-overlapped union U (48 MB)
  char* U = alloc((size_t)48 * 1024 * 1024);
  bf16*  xln_b  = (bf16*)(U);                              // 16 MB (attn+mlp)
  float* dots_f = (float*)(U + (size_t)16 * 1024 * 1024);  // 16 MB (attn)
  bf16*  rz_b   = (bf16*)(U);                              // 32 MB (gru)
  bf16*  hn_b   = (bf16*)(U + (size_t)32 * 1024 * 1024);   // 16 MB (gru)
  bf16*  h1_b   = (bf16*)(U + (size_t)16 * 1024 * 1024);   // 32 MB (mlp)

  if (ws_size < off) return;  // fail loudly instead of faulting

  float* slots_f = (float*)d_out;

  // ---- weight prep ----
  f2b<<<dim3(D * D / 1024), 256, 0, stream>>>(Wk, wk_b);
  f2b<<<dim3(D * D / 1024), 256, 0, stream>>>(Wv, wv_b);
  f2b<<<dim3(H * D / 1024), 256, 0, stream>>>(W1, w1_b);
  f2b<<<dim3(D * H / 1024), 256, 0, stream>>>(W2, w2_b);
  f2b<<<dim3(D * D / 1024), 256, 0, stream>>>(Whh + (size_t)2048 * D, whn_b);
  f2b<<<dim3(D * D / 1024), 256, 0, stream>>>(Wih + (size_t)2048 * D, win_b);
  f2b<<<dim3(2048 * D / 1024), 256, 0, stream>>>(Wih, wihrz_b);
  f2b_T<<<dim3(D * D / 256), 256, 0, stream>>>(Wq, wqT_b);
  // Whh rows 0:2047 -> wcat2 cols [512,1536)
  f2b_ld<<<dim3(2048 * 1024 / 256), 256, 0, stream>>>(Whh, wcat2_b + 512, 1536);
  make_brz<<<dim3(8), 256, 0, stream>>>(bih, bhh, brz_b);

  init_slots<<<dim3(M * D / 1024), 256, 0, stream>>>(inputs, slots_f, xcat2_b + 512);

  // ---- iteration-invariant tensors ----
  ln_rows<<<dim3(J), 256, 0, stream>>>(texts, g_in, be_in, texts_n, D);
  // k = LN(texts) @ Wk^T + bk
  gemm_bt<64><<<dim3(J / 128, D / 64), 256, 0, stream>>>(
      texts_n, D, wk_b, D, bk, J, D, D, 1.f, 0,
      nullptr, 0, k_b, D, nullptr, nullptr, nullptr, nullptr, nullptr);
  // v = LN(texts) @ Wv^T + bv
  gemm_bt<64><<<dim3(J / 128, D / 64), 256, 0, stream>>>(
      texts_n, D, wv_b, D, bv, J, D, D, 1.f, 0,
      nullptr, 0, v_b, D, nullptr, nullptr, nullptr, nullptr, nullptr);
  // kq = k @ Wq
  gemm_bt<64><<<dim3(J / 128, D / 64), 256, 0, stream>>>(
      k_b, D, wqT_b, D, nullptr, J, D, D, 1.f, 0,
      nullptr, 0, kq_b, D, nullptr, nullptr, nullptr, nullptr, nullptr);
  // PT_rz = Wih_rz @ v^T -> wcat2 cols [0,512)
  gemm_bt<64><<<dim3(2048 / 128, J / 64), 256, 0, stream>>>(
      wihrz_b, D, v_b, D, nullptr, 2048, J, D, 1.f, 0,
      nullptr, 0, wcat2_b, 1536, nullptr, nullptr, nullptr, nullptr, nullptr);
  // PT_n = Wih_n @ v^T -> ptn [1024 x 512]
  gemm_bt<64><<<dim3(D / 128, J / 64), 256, 0, stream>>>(
      win_b, D, v_b, D, nullptr, D, J, D, 1.f, 0,
      nullptr, 0, ptn_b, J, nullptr, nullptr, nullptr, nullptr, nullptr);
  make_bqk<<<dim3(2), 256, 0, stream>>>(k_b, bq, bqk_b, SCALE);
  make_vcol<<<dim3(4), 256, 0, stream>>>(v_b, vcol_b);
  make_c<<<dim3(3072), 256, 0, stream>>>(Wih, vcol_b, c_b);

  for (int it = 0; it < 3; it++) {
    // xln = LN(slots)
    ln_rows<<<dim3(M), 256, 0, stream>>>(slots_f, g_sl, be_sl, xln_b, D);
    // dots = SCALE*(xln @ kq^T) + bqk
    gemm_bt<64><<<dim3(M / 128, J / 64), 256, 0, stream>>>(
        xln_b, D, kq_b, D, bqk_b, M, J, D, SCALE, 0,
        dots_f, J, nullptr, 0, nullptr, nullptr, nullptr, nullptr, nullptr);
    // softmax over slots axis -> xcat2 cols [0,512); row partials -> P
    softmax_fused<<<dim3(B, 8), 256, 0, stream>>>(dots_f, xcat2_b, P_b);
    rowinv_k<<<dim3(M / 256), 256, 0, stream>>>(P_b, rinv_b);
    smscale<<<dim3(M * 512 / 256), 256, 0, stream>>>(xcat2_b, rinv_b);
    // h_n = slots @ Whh_n^T + bhh_n
    gemm_bt<64><<<dim3(M / 128, D / 64), 256, 0, stream>>>(
        xcat2_b + 512, 1536, whn_b, D, bhh + 2048, M, D, D, 1.f, 0,
        nullptr, 0, hn_b, D, nullptr, nullptr, nullptr, nullptr, nullptr);
    // rz = sigmoid([sm2|slots] @ [PT_rz|Whh_rz]^T + brz + eps*rinv*c_rz)
    gemm_bt<128><<<dim3(M / 128, 2048 / 128), 256, 0, stream>>>(
        xcat2_b, 1536, wcat2_b, 1536, brz_b, M, 2048, 1536, 1.f, F_SIGMOID | F_EPSC,
        nullptr, 0, rz_b, 2048, nullptr, nullptr, nullptr, c_b, rinv_b);
    // i_n = sm2 @ PT_n^T + bih_n + eps*rinv*c_n; fused GRU epilogue
    gemm_bt<64><<<dim3(M / 128, D / 64), 256, 0, stream>>>(
        xcat2_b, 1536, ptn_b, J, bih + 2048, M, D, J, 1.f, F_GRU | F_EPSC,
        slots_f, D, xcat2_b + 512, 1536, slots_f, rz_b, hn_b, c_b + 2048, rinv_b);
    // MLP residual, H split into two 2048 halves
    ln_rows<<<dim3(M), 256, 0, stream>>>(slots_f, g_ff, be_ff, xln_b, D);
    gemm_bt<128><<<dim3(M / 128, 2048 / 128), 256, 0, stream>>>(
        xln_b, D, w1_b, D, b1, M, 2048, D, 1.f, F_RELU,
        nullptr, 0, h1_b, 2048, nullptr, nullptr, nullptr, nullptr, nullptr);
    gemm_bt<64><<<dim3(M / 128, D / 64), 256, 0, stream>>>(
        h1_b, 2048, w2_b, H, b2, M, D, 2048, 1.f, 0,
        slots_f, D, nullptr, 0, slots_f, nullptr, nullptr, nullptr, nullptr);
    gemm_bt<128><<<dim3(M / 128, 2048 / 128), 256, 0, stream>>>(
        xln_b, D, w1_b + (size_t)2048 * D, D, b1 + 2048, M, 2048, D, 1.f, F_RELU,
        nullptr, 0, h1_b, 2048, nullptr, nullptr, nullptr, nullptr, nullptr);
    gemm_bt<64><<<dim3(M / 128, D / 64), 256, 0, stream>>>(
        h1_b, 2048, w2_b + 2048, H, nullptr, M, D, 2048, 1.f, 0,
        slots_f, D, xcat2_b + 512, 1536, slots_f, nullptr, nullptr, nullptr, nullptr);
  }
}